// Round 4
// baseline (216.215 us; speedup 1.0000x reference)
//
#include <hip/hip_runtime.h>
#include <hip/hip_bf16.h>

#define BATCH 4
#define CCH   256
#define HWHW  4096
#define NSP   256
#define NHEAD 8
#define SCALE 0.17677669529663689f
#define PLANE 1048576L

typedef short bf16x8 __attribute__((ext_vector_type(8)));
typedef short bf16x4 __attribute__((ext_vector_type(4)));
typedef float f32x4  __attribute__((ext_vector_type(4)));

__device__ __forceinline__ short f2bs(float f) {
    __hip_bfloat16 h = __float2bfloat16(f);
    return *(short*)&h;
}
__device__ __forceinline__ bf16x8 cvt8(float4 a, float4 b) {
    bf16x8 p;
    p[0] = f2bs(a.x); p[1] = f2bs(a.y); p[2] = f2bs(a.z); p[3] = f2bs(a.w);
    p[4] = f2bs(b.x); p[5] = f2bs(b.y); p[6] = f2bs(b.z); p[7] = f2bs(b.w);
    return p;
}
// async global->LDS, 16B per lane; LDS dest = base + lane*16 (wave-uniform base)
__device__ __forceinline__ void gll16(const __hip_bfloat16* g, __hip_bfloat16* l) {
    __builtin_amdgcn_global_load_lds(
        (const __attribute__((address_space(1))) unsigned int*)(const void*)g,
        (__attribute__((address_space(3))) unsigned int*)(void*)l,
        16, 0, 0);
}

// ---------------------------------------------------------------------------
// Fused LayerNorm -> xn_cn [b][c][n] + xn_nc [b][n][c] (bf16), register-
// resident: 512 thr/block, thread owns 8 channels x 4 pixels. Blocks 256..259: W casts.
__global__ __launch_bounds__(512)
void ln_fused_kernel(const float* __restrict__ x, const float* __restrict__ w,
                     const float* __restrict__ bb,
                     const float* __restrict__ Wq, const float* __restrict__ Wk,
                     const float* __restrict__ Wv, const float* __restrict__ Wsp,
                     __hip_bfloat16* __restrict__ xn_cn,
                     __hip_bfloat16* __restrict__ xn_nc,
                     __hip_bfloat16* __restrict__ wbf)
{
    __shared__ float ps[32][64], pss[32][64];
    __shared__ float mus[64], rstds[64];
    __shared__ float wls[256], bls[256];
    int blk = blockIdx.x;
    int t = threadIdx.x;
    if (blk >= 256) {                        // weight casts
        int sel = blk - 256;
        const float* src = (sel == 0) ? Wq : (sel == 1) ? Wk : (sel == 2) ? Wv : Wsp;
        __hip_bfloat16* dst = wbf + sel * 65536;
        for (int i = t * 4; i < 65536; i += 2048) {
            float4 f = *(const float4*)(src + i);
            __hip_bfloat16 p[4];
            p[0] = __float2bfloat16(f.x); p[1] = __float2bfloat16(f.y);
            p[2] = __float2bfloat16(f.z); p[3] = __float2bfloat16(f.w);
            *(int2*)(dst + i) = *(int2*)p;
        }
        return;
    }
    int b = blk >> 6;
    int n0 = (blk & 63) * 64;
    int pg = t & 15;                         // pixel group: 4 pixels
    int cq = t >> 4;                         // channel group: 8 channels
    if (t < 256) { wls[t] = w[t]; bls[t] = bb[t]; }

    const float* xp = x + ((long)(b * CCH + cq * 8)) * HWHW + n0 + pg * 4;
    float4 v[8];
#pragma unroll
    for (int i = 0; i < 8; ++i) v[i] = *(const float4*)(xp + (long)i * HWHW);
    float4 s = {0.f,0.f,0.f,0.f}, ss = {0.f,0.f,0.f,0.f};
#pragma unroll
    for (int i = 0; i < 8; ++i) {
        s.x += v[i].x; s.y += v[i].y; s.z += v[i].z; s.w += v[i].w;
        ss.x += v[i].x * v[i].x; ss.y += v[i].y * v[i].y;
        ss.z += v[i].z * v[i].z; ss.w += v[i].w * v[i].w;
    }
    *(float4*)&ps[cq][pg * 4]  = s;
    *(float4*)&pss[cq][pg * 4] = ss;
    __syncthreads();
    if (t < 64) {
        float S = 0.f, SS = 0.f;
#pragma unroll
        for (int q = 0; q < 32; ++q) { S += ps[q][t]; SS += pss[q][t]; }
        float mu = S * (1.f / 256.f);
        float var = SS * (1.f / 256.f) - mu * mu;
        mus[t] = mu; rstds[t] = rsqrtf(var + 1e-6f);
    }
    __syncthreads();
    float4 mu4 = *(float4*)&mus[pg * 4];
    float4 rs4 = *(float4*)&rstds[pg * 4];

    bf16x8 pk[4];                            // [pixel j][channel i]
#pragma unroll
    for (int i = 0; i < 8; ++i) {
        int c = cq * 8 + i;
        float wc = wls[c], bc = bls[c];
        short h0 = f2bs((v[i].x - mu4.x) * rs4.x * wc + bc);
        short h1 = f2bs((v[i].y - mu4.y) * rs4.y * wc + bc);
        short h2 = f2bs((v[i].z - mu4.z) * rs4.z * wc + bc);
        short h3 = f2bs((v[i].w - mu4.w) * rs4.w * wc + bc);
        pk[0][i] = h0; pk[1][i] = h1; pk[2][i] = h2; pk[3][i] = h3;
        bf16x4 q; q[0] = h0; q[1] = h1; q[2] = h2; q[3] = h3;
        *(bf16x4*)(xn_cn + ((long)(b * CCH + c)) * HWHW + n0 + pg * 4) = q;
    }
#pragma unroll
    for (int j = 0; j < 4; ++j)
        *(bf16x8*)(xn_nc + ((long)b * HWHW + n0 + pg * 4 + j) * CCH + cq * 8) = pk[j];
}

// ---------------------------------------------------------------------------
// K=256 one-shot GEMM: stage full A-tile (64x256 bf16 = 32KB) into LDS once
// (8 gll16/wave), ONE barrier, then 32 MFMAs/wave with B fragments read
// directly from global (L2/L3-resident operands). Zero K-loop barriers.
// C[m][n] = sum_k A[m][k]*B[n][k], bf16 out. Accumulation order = kslot
// ascending (identical to the BK=64/kh loop -> bit-identical results).
__device__ __forceinline__ void gemm_k256_oneshot(
    const __hip_bfloat16* __restrict__ A, const __hip_bfloat16* __restrict__ B,
    __hip_bfloat16* __restrict__ C, int bx, int by, int bz,
    int N, long aStrideZ, long bStrideZ, long cStrideZ,
    __hip_bfloat16* __restrict__ Asm)
{
    const int K = 256;
    const int t = threadIdx.x, lane = t & 63, w = t >> 6;
    const int l15 = lane & 15, quad = lane >> 4;
    const int Mt = by * 64, Nt = bx * 64;
    // stage A: wave w owns rows [w*16, w*16+16); slab (w*8+p) = 512 bf16
    const __hip_bfloat16* aSrc = A + (long)bz * aStrideZ
        + (long)(Mt + w * 16 + l15) * K + quad * 8;
#pragma unroll
    for (int p = 0; p < 8; ++p)
        gll16(aSrc + p * 32, Asm + ((w * 8 + p) << 9));

    const int wm = (w & 1) * 2, wn = (w >> 1) * 2;
    const __hip_bfloat16* b0p = B + (long)bz * bStrideZ
        + (long)(Nt + wn * 16 + l15) * K + quad * 8;
    const __hip_bfloat16* b1p = b0p + 16 * K;
    f32x4 acc00 = {0.f,0.f,0.f,0.f}, acc01 = acc00, acc10 = acc00, acc11 = acc00;
    __syncthreads();                          // single drain: A tile ready
#pragma unroll
    for (int s = 0; s < 8; ++s) {
        bf16x8 a0 = *(const bf16x8*)&Asm[((wm * 8 + s) << 9) + lane * 8];
        bf16x8 a1 = *(const bf16x8*)&Asm[(((wm + 1) * 8 + s) << 9) + lane * 8];
        bf16x8 b0 = *(const bf16x8*)(b0p + s * 32);
        bf16x8 b1 = *(const bf16x8*)(b1p + s * 32);
        acc00 = __builtin_amdgcn_mfma_f32_16x16x32_bf16(a0, b0, acc00, 0, 0, 0);
        acc01 = __builtin_amdgcn_mfma_f32_16x16x32_bf16(a0, b1, acc01, 0, 0, 0);
        acc10 = __builtin_amdgcn_mfma_f32_16x16x32_bf16(a1, b0, acc10, 0, 0, 0);
        acc11 = __builtin_amdgcn_mfma_f32_16x16x32_bf16(a1, b1, acc11, 0, 0, 0);
    }
    f32x4 accs[2][2] = {{acc00, acc01}, {acc10, acc11}};
#pragma unroll
    for (int i = 0; i < 2; ++i)
#pragma unroll
        for (int j = 0; j < 2; ++j)
#pragma unroll
            for (int r = 0; r < 4; ++r) {
                int m = Mt + (wm + i) * 16 + quad * 4 + r;
                int n = Nt + (wn + j) * 16 + l15;
                C[(long)bz * cStrideZ + (long)m * N + n] =
                    __float2bfloat16(accs[i][j][r]);
            }
}

// ---------------------------------------------------------------------------
// bf16 MFMA NT GEMM body, BK=64 (for large-K / fp32-A cases).
// ASTAGE: 1 = A fp32 reg-convert (prefetched);
//         2 = A = sum of 8 fp32 planes (stride 65536) + fused rowscale (rsl).
// ROWSUM: emit rsPart[z*256+m].  NTL: N-tiles per block.
template <int OUTK, int ASTAGE, bool ROWSUM, int NTL>
__device__ __forceinline__ void gemm_body(
    const void* __restrict__ Av, const __hip_bfloat16* __restrict__ B,
    void* __restrict__ Cptr, int bx, int by, int bz,
    int N, int K, int kChunk, int kShift,
    long aStrideZ, long bStrideZ, long cStrideZ,
    float* __restrict__ rsPart,
    __hip_bfloat16* __restrict__ Asm, __hip_bfloat16* __restrict__ Bsm,
    float* __restrict__ rsl)
{
    int z = bz;
    int b = z >> kShift;
    int ch = z & ((1 << kShift) - 1);
    int t = threadIdx.x;
    int lane = t & 63, w = t >> 6;
    int l15 = lane & 15, quad = lane >> 4;
    int Mt = by * 64, Nt = bx * 64 * NTL;

    if (ASTAGE == 2 && t < 64) {             // fused rowsum reduce (8 chunks)
        float s = 0.f;
#pragma unroll
        for (int pl = 0; pl < 8; ++pl) s += rsPart[((b * 8 + pl) << 8) + Mt + t];
        rsl[t] = s;
    }

    long aOff = (long)b * aStrideZ + (long)ch * kChunk
        + (long)(Mt + w * 16 + l15) * K + quad * 8;
    const float* aSrcF = (const float*)Av + aOff;
    const __hip_bfloat16* bSrc = B + (long)b * bStrideZ + (long)ch * kChunk
        + (long)(Nt + w * 16 + l15) * K + quad * 8;

    f32x4 acc[NTL][2][2];
#pragma unroll
    for (int nt = 0; nt < NTL; ++nt)
#pragma unroll
        for (int i = 0; i < 2; ++i)
#pragma unroll
            for (int j = 0; j < 2; ++j) acc[nt][i][j] = f32x4{0.f,0.f,0.f,0.f};
    f32x4 rs0 = {0.f,0.f,0.f,0.f}, rs1 = rs0;
    bf16x8 onesf;
    { short o = (l15 == 0) ? (short)0x3F80 : (short)0;
      onesf = bf16x8{o, o, o, o, o, o, o, o}; }
    int wm = (w & 1) * 2, wn = (w >> 1) * 2;

    float4 pf0, pf1, pf2, pf3;
    if (ASTAGE == 1) {
        pf0 = *(const float4*)(aSrcF);      pf1 = *(const float4*)(aSrcF + 4);
        pf2 = *(const float4*)(aSrcF + 32); pf3 = *(const float4*)(aSrcF + 36);
    }

    const bf16x8* AsmU = (const bf16x8*)Asm;
    const bf16x8* BsmU = (const bf16x8*)Bsm;

    for (int k0 = 0; k0 < kChunk; k0 += 64) {
        // ---- stage A ----
        if (ASTAGE == 1) {
            *(bf16x8*)&Asm[t * 8]        = cvt8(pf0, pf1);
            *(bf16x8*)&Asm[2048 + t * 8] = cvt8(pf2, pf3);
        } else {                              // 8-plane fp32 sum
#pragma unroll
            for (int kh = 0; kh < 2; ++kh) {
                float4 s0 = {0.f,0.f,0.f,0.f}, s1 = {0.f,0.f,0.f,0.f};
#pragma unroll
                for (int pl = 0; pl < 8; ++pl) {
                    const float* p = aSrcF + (long)pl * 65536 + k0 + kh * 32;
                    float4 u0 = *(const float4*)p, u1 = *(const float4*)(p + 4);
                    s0.x += u0.x; s0.y += u0.y; s0.z += u0.z; s0.w += u0.w;
                    s1.x += u1.x; s1.y += u1.y; s1.z += u1.z; s1.w += u1.w;
                }
                *(bf16x8*)&Asm[kh * 2048 + t * 8] = cvt8(s0, s1);
            }
        }
        // ---- stage B (bf16, async direct-to-LDS) ----
#pragma unroll
        for (int nt = 0; nt < NTL; ++nt) {
            gll16(bSrc + (long)nt * 64 * K + k0,      Bsm + nt * 4096 + w * 512);
            gll16(bSrc + (long)nt * 64 * K + k0 + 32, Bsm + nt * 4096 + 2048 + w * 512);
        }
        __syncthreads();
        if (ASTAGE == 1 && k0 + 64 < kChunk) {   // prefetch next A chunk
            const float* nx = aSrcF + k0 + 64;
            pf0 = *(const float4*)nx;        pf1 = *(const float4*)(nx + 4);
            pf2 = *(const float4*)(nx + 32); pf3 = *(const float4*)(nx + 36);
        }
        // ---- MFMA ----
#pragma unroll
        for (int kh = 0; kh < 2; ++kh) {
            bf16x8 a0 = AsmU[kh * 256 + wm * 64 + lane];
            bf16x8 a1 = AsmU[kh * 256 + (wm + 1) * 64 + lane];
            if (ROWSUM) {
                rs0 = __builtin_amdgcn_mfma_f32_16x16x32_bf16(a0, onesf, rs0, 0, 0, 0);
                rs1 = __builtin_amdgcn_mfma_f32_16x16x32_bf16(a1, onesf, rs1, 0, 0, 0);
            }
#pragma unroll
            for (int nt = 0; nt < NTL; ++nt) {
                bf16x8 b0 = BsmU[nt * 512 + kh * 256 + wn * 64 + lane];
                bf16x8 b1 = BsmU[nt * 512 + kh * 256 + (wn + 1) * 64 + lane];
                acc[nt][0][0] = __builtin_amdgcn_mfma_f32_16x16x32_bf16(a0, b0, acc[nt][0][0], 0, 0, 0);
                acc[nt][0][1] = __builtin_amdgcn_mfma_f32_16x16x32_bf16(a0, b1, acc[nt][0][1], 0, 0, 0);
                acc[nt][1][0] = __builtin_amdgcn_mfma_f32_16x16x32_bf16(a1, b0, acc[nt][1][0], 0, 0, 0);
                acc[nt][1][1] = __builtin_amdgcn_mfma_f32_16x16x32_bf16(a1, b1, acc[nt][1][1], 0, 0, 0);
            }
        }
        __syncthreads();
    }
    if (ROWSUM && bx == 0 && (w >> 1) == 0 && l15 == 0) {
#pragma unroll
        for (int r = 0; r < 4; ++r) {
            rsPart[(long)z * 256 + Mt + wm * 16 + quad * 4 + r]       = rs0[r];
            rsPart[(long)z * 256 + Mt + (wm + 1) * 16 + quad * 4 + r] = rs1[r];
        }
    }
#pragma unroll
    for (int nt = 0; nt < NTL; ++nt)
#pragma unroll
        for (int i = 0; i < 2; ++i)
#pragma unroll
            for (int j = 0; j < 2; ++j)
#pragma unroll
                for (int r = 0; r < 4; ++r) {
                    int m = Mt + (wm + i) * 16 + quad * 4 + r;
                    int n = Nt + nt * 64 + (wn + j) * 16 + l15;
                    float val = acc[nt][i][j][r];
                    if (ASTAGE == 2) val /= (rsl[m - Mt] + 1e-16f);
                    long off = (long)z * cStrideZ + (long)m * N + n;
                    if (OUTK == 0) ((float*)Cptr)[off] = val;
                    else ((__hip_bfloat16*)Cptr)[off] = __float2bfloat16(val);
                }
}

// mega1: stoken partials [0,128) NTL=4 | q+k one-shot [128,2176) | v one-shot [2176,3200)
__global__ __launch_bounds__(256, 4)
void mega1_kernel(const float* __restrict__ aff,
                  const __hip_bfloat16* __restrict__ xn_cn,
                  const __hip_bfloat16* __restrict__ xn_nc,
                  const __hip_bfloat16* __restrict__ wbf,
                  __hip_bfloat16* __restrict__ qk_nc,
                  __hip_bfloat16* __restrict__ v_cn,
                  float* __restrict__ stoken_part,
                  float* __restrict__ rs_part)
{
    __shared__ __align__(16) char smem[40960];
    __hip_bfloat16* Asm = (__hip_bfloat16*)smem;            // stoken: 8KB
    __hip_bfloat16* Bsm = (__hip_bfloat16*)(smem + 8192);   // stoken: 32KB
    __hip_bfloat16* Aos = (__hip_bfloat16*)smem;            // one-shot: 32KB
    int blk = blockIdx.x;
    if (blk < 128) {          // stoken partials (longest path first)
        int i = blk;
        gemm_body<0, 1, true, 4>(aff, xn_cn, stoken_part,
            0, i & 3, i >> 2, 256, 4096, 512, 3,
            PLANE, PLANE, 65536L, rs_part, Asm, Bsm, nullptr);
    } else if (blk < 2176) {  // fused q+k: A=xn_nc rows, B=weights (direct)
        int i = blk - 128;
        gemm_k256_oneshot(xn_nc, wbf, qk_nc,
            i & 7, (i >> 3) & 63, i >> 9, 512, PLANE, 0L, 2 * PLANE, Aos);
    } else {                  // v_cn: A=Wv rows, B=xn_nc rows (direct)
        int i = blk - 2176;
        gemm_k256_oneshot(wbf + 2 * 65536, xn_nc, v_cn,
            i & 63, (i >> 6) & 3, i >> 8, 4096, 0L, PLANE, PLANE, Aos);
    }
}

// st_md = (sum_ch stoken_part)·Wsp / (rowsum+eps)  — fused split-K reduce
__global__ __launch_bounds__(256)
void stmd_kernel(const float* __restrict__ part,
                 const __hip_bfloat16* __restrict__ wsp,
                 __hip_bfloat16* __restrict__ st_md,
                 float* __restrict__ rs_part)
{
    __shared__ __hip_bfloat16 Asm[4096];
    __shared__ __hip_bfloat16 Bsm[4096];
    __shared__ float rsl[64];
    int i = blockIdx.x;
    gemm_body<1, 2, false, 1>(part, wsp, st_md,
        i & 3, (i >> 2) & 3, i >> 4, 256, 256, 256, 0,
        524288L, 0L, 65536L, rs_part, Asm, Bsm, rsl);
}

// ---------------------------------------------------------------------------
// Stage-1 MFMA attention partials (device fn; smem carved by mega2).
__device__ __forceinline__
void stage1_dev(char* smem, int chunk, int bh,
                const __hip_bfloat16* __restrict__ qk_nc,
                const __hip_bfloat16* __restrict__ v_cn,
                const __hip_bfloat16* __restrict__ st_md,
                __hip_bfloat16* __restrict__ opart)
{
    __hip_bfloat16* Es  = (__hip_bfloat16*)smem;            // 256*72*2 = 36864
    __hip_bfloat16* sts = (__hip_bfloat16*)(smem + 36864);  // 256*40*2 = 20480
    const int b = bh >> 3, h = bh & 7;
    const int t = threadIdx.x, lane = t & 63, w = t >> 6;
    const int l15 = lane & 15, quad = lane >> 4;
    const int n0 = chunk * 256;

    {
        const int4* src = (const int4*)(st_md + ((long)(b * 256 + t)) * 256 + h * 32);
        int4* dst = (int4*)&sts[t * 40];
        dst[0] = src[0]; dst[1] = src[1]; dst[2] = src[2]; dst[3] = src[3];
    }
    __syncthreads();
    bf16x8 afrag[16];
#pragma unroll
    for (int mt = 0; mt < 16; ++mt)
        afrag[mt] = *(const bf16x8*)&sts[(mt * 16 + l15) * 40 + quad * 8];
    bf16x8 onesf;
    { short o = (l15 == 0) ? (short)0x3F80 : (short)0;
      onesf = bf16x8{o, o, o, o, o, o, o, o}; }

    f32x4 occ[4][3];
#pragma unroll
    for (int i = 0; i < 4; ++i)
#pragma unroll
        for (int j = 0; j < 3; ++j) occ[i][j] = f32x4{0.f,0.f,0.f,0.f};

    for (int sub = 0; sub < 4; ++sub) {
        const int nbase = n0 + sub * 64;
        bf16x8 kf = *(const bf16x8*)(qk_nc + ((long)b * 4096 + nbase + 16 * w + l15) * 512 + 256 + h * 32 + quad * 8);
#pragma unroll
        for (int mt = 0; mt < 16; ++mt) {
            f32x4 s = __builtin_amdgcn_mfma_f32_16x16x32_bf16(afrag[mt], kf, f32x4{0.f,0.f,0.f,0.f}, 0, 0, 0);
#pragma unroll
            for (int r = 0; r < 4; ++r)
                Es[(mt * 16 + quad * 4 + r) * 72 + 16 * w + l15] =
                    __float2bfloat16(__expf(s[r] * SCALE));
        }
        __syncthreads();
#pragma unroll
        for (int ks = 0; ks < 2; ++ks) {
            bf16x8 bf0 = *(const bf16x8*)(v_cn + ((long)(b * 256 + h * 32 + l15)) * 4096 + nbase + ks * 32 + quad * 8);
            bf16x8 bf1 = *(const bf16x8*)(v_cn + ((long)(b * 256 + h * 32 + 16 + l15)) * 4096 + nbase + ks * 32 + quad * 8);
#pragma unroll
            for (int mi = 0; mi < 4; ++mi) {
                bf16x8 af = *(const bf16x8*)&Es[(64 * w + mi * 16 + l15) * 72 + ks * 32 + quad * 8];
                occ[mi][0] = __builtin_amdgcn_mfma_f32_16x16x32_bf16(af, bf0, occ[mi][0], 0, 0, 0);
                occ[mi][1] = __builtin_amdgcn_mfma_f32_16x16x32_bf16(af, bf1, occ[mi][1], 0, 0, 0);
                occ[mi][2] = __builtin_amdgcn_mfma_f32_16x16x32_bf16(af, onesf, occ[mi][2], 0, 0, 0);
            }
        }
        __syncthreads();
    }
    // transpose partials through LDS (Es dead): tb[col][m], pitch 264 bf16
    __hip_bfloat16* tb = Es;
#pragma unroll
    for (int mi = 0; mi < 4; ++mi)
#pragma unroll
        for (int jt = 0; jt < 3; ++jt) {
            if (jt == 2 && l15 != 0) continue;
            int col = jt * 16 + l15;
#pragma unroll
            for (int r = 0; r < 4; ++r) {
                int m = 64 * w + mi * 16 + quad * 4 + r;
                tb[col * 264 + m] = __float2bfloat16(occ[mi][jt][r]);
            }
        }
    __syncthreads();
    // coalesced global write: 33 rows x 256 bf16 = 4224 ints
    int* og = (int*)(opart) + (long)(chunk * 32 + bh) * 4224;
    const int* tbi = (const int*)tb;
#pragma unroll
    for (int i = 0; i < 17; ++i) {
        int idx = t + i * 256;
        if (idx < 4224) {
            int row = idx >> 7, off = idx & 127;
            og[idx] = tbi[row * 132 + off];
        }
    }
}

// Depthwise 3x3 conv + scramble-transpose (device fn; smem carved by mega2).
__device__ __forceinline__
void lepe_dev(char* smem, int bx, int cy, int b,
              const __hip_bfloat16* __restrict__ v_cn,
              const float* __restrict__ lw, const float* __restrict__ lb,
              __hip_bfloat16* __restrict__ lepe_cn)
{
    __hip_bfloat16* in_t    = (__hip_bfloat16*)smem;            // 32*384*2 = 24576
    __hip_bfloat16* tile_bf = (__hip_bfloat16*)(smem + 24576);  // 256*33*2 = 16896
    float* wls = (float*)(smem + 41472);                        // 288*4
    float* bls = (float*)(smem + 42624);                        // 32*4
    const int c0 = cy * 32;
    const int t = threadIdx.x;
    const int n0 = bx * 256, r0 = bx * 4;

    for (int i = t; i < 288; i += 256) wls[i] = lw[c0 * 9 + i];
    if (t < 32)  bls[t] = lb[c0 + t];
#pragma unroll
    for (int i = 0; i < 6; ++i) {
        int vi = t + i * 256;
        int ch = vi / 48;
        int off = (vi % 48) * 8;
        int g = (r0 - 1) * 64 + off;
        int4 val = {0, 0, 0, 0};
        if ((unsigned)g < 4096u)
            val = *(const int4*)(v_cn + (((long)(b * CCH + c0 + ch)) << 12) + g);
        *(int4*)&in_t[ch * 384 + off] = val;
    }
    __syncthreads();

    const int lane = t & 63, w = t >> 6;
#pragma unroll
    for (int i = 0; i < 8; ++i) {
        int ch = w * 8 + i;
        float cr[6], lf[6], rf[6];
#pragma unroll
        for (int rr = 0; rr < 6; ++rr) {
            cr[rr] = (float)in_t[ch * 384 + rr * 64 + lane];
            float lv = __shfl_up(cr[rr], 1);
            float rv = __shfl_down(cr[rr], 1);
            lf[rr] = (lane == 0) ? 0.f : lv;
            rf[rr] = (lane == 63) ? 0.f : rv;
        }
        float w0 = wls[ch*9+0], w1 = wls[ch*9+1], w2 = wls[ch*9+2];
        float w3 = wls[ch*9+3], w4 = wls[ch*9+4], w5 = wls[ch*9+5];
        float w6 = wls[ch*9+6], w7 = wls[ch*9+7], w8 = wls[ch*9+8];
        float bias = bls[ch];
#pragma unroll
        for (int r = 0; r < 4; ++r) {
            float acc = bias
                + lf[r]   * w0 + cr[r]   * w1 + rf[r]   * w2
                + lf[r+1] * w3 + cr[r+1] * w4 + rf[r+1] * w5
                + lf[r+2] * w6 + cr[r+2] * w7 + rf[r+2] * w8;
            tile_bf[(r * 64 + lane) * 33 + ch] = __float2bfloat16(acc);
        }
    }
    __syncthreads();
#pragma unroll
    for (int i = 0; i < 32; ++i) {
        int idx = t + i * 256;
        int nl = idx >> 5, cj = idx & 31;
        int sp = n0 + nl;
        lepe_cn[((long)(b * CCH + (sp >> 4)) << 12) + (nl & 15) * 256 + c0 + cj] =
            tile_bf[nl * 33 + cj];
    }
}

// mega2: stage1 [0,512) | lepe [512,1024)
__global__ __launch_bounds__(256)
void mega2_kernel(const __hip_bfloat16* __restrict__ qk_nc,
                  const __hip_bfloat16* __restrict__ v_cn,
                  const __hip_bfloat16* __restrict__ st_md,
                  __hip_bfloat16* __restrict__ opart,
                  const float* __restrict__ lw, const float* __restrict__ lb,
                  __hip_bfloat16* __restrict__ lepe_cn)
{
    __shared__ __align__(16) char smem[57344];
    int blk = blockIdx.x;
    if (blk < 512) {
        stage1_dev(smem, blk & 15, blk >> 4, qk_nc, v_cn, st_md, opart);
    } else {
        int j = blk - 512;
        lepe_dev(smem, j & 15, (j >> 4) & 7, j >> 7, v_cn, lw, lb, lepe_cn);
    }
}

// Merge stage-1 partials -> sout_bf[bh][d][m]  (coalesced bf16 reads)
__global__ __launch_bounds__(256)
void merge1_kernel(const __hip_bfloat16* __restrict__ opart, __hip_bfloat16* __restrict__ sout)
{
    int t = blockIdx.x * 256 + threadIdx.x;   // 262144
    int m = t & 255;
    int d = (t >> 8) & 31;
    int bh = t >> 13;
    float num = 0.f, den = 0.f;
    for (int ch = 0; ch < 16; ++ch) {
        long base = (long)((ch * 32 + bh) * 33) * 256 + m;
        num += (float)opart[base + (long)d * 256];
        den += (float)opart[base + 32 * 256];
    }
    sout[(long)bh * 8192 + d * 256 + m] = __float2bfloat16(num / den);
}

// ---------------------------------------------------------------------------
// Stage-2 MFMA attention + lepe add.  Writes final out[b][c][n].
__global__ __launch_bounds__(256)
void stage2_mfma(const __hip_bfloat16* __restrict__ qk_nc,
                 const __hip_bfloat16* __restrict__ st_md,
                 const __hip_bfloat16* __restrict__ sout_bf,
                 const __hip_bfloat16* __restrict__ lepe_cn,
                 float* __restrict__ out)
{
    __shared__ __hip_bfloat16 Es2[64 * 264];
    __shared__ __hip_bfloat16 sts[256 * 40];
    __shared__ __hip_bfloat16 sos[32 * 264];
    __shared__ float o_t[32 * 68];
    const int chunk = blockIdx.x, bh = blockIdx.y;
    const int b = bh >> 3, h = bh & 7;
    const int t = threadIdx.x, lane = t & 63, w = t >> 6;
    const int l15 = lane & 15, quad = lane >> 4;
    const int n0 = chunk * 256;

    {
        const int4* src = (const int4*)(st_md + ((long)(b * 256 + t)) * 256 + h * 32);
        int4* dst = (int4*)&sts[t * 40];
        dst[0] = src[0]; dst[1] = src[1]; dst[2] = src[2]; dst[3] = src[3];
    }
    {
        int row = t >> 3, seg = t & 7;
        const int4* src = (const int4*)(sout_bf + (long)bh * 8192 + row * 256 + seg * 32);
        int4* dst = (int4*)&sos[row * 264 + seg * 32];
        dst[0] = src[0]; dst[1] = src[1]; dst[2] = src[2]; dst[3] = src[3];
    }
    __syncthreads();
    bf16x8 stfrag[4];
#pragma unroll
    for (int mt = 0; mt < 4; ++mt)
        stfrag[mt] = *(const bf16x8*)&sts[(64 * w + mt * 16 + l15) * 40 + quad * 8];
    bf16x8 onesf;
    { short o = (l15 == 0) ? (short)0x3F80 : (short)0;
      onesf = bf16x8{o, o, o, o, o, o, o, o}; }

    for (int sub = 0; sub < 4; ++sub) {
        const int nbase = n0 + sub * 64;
#pragma unroll
        for (int nt = 0; nt < 4; ++nt) {
            bf16x8 qf = *(const bf16x8*)(qk_nc + ((long)b * 4096 + nbase + nt * 16 + l15) * 512 + h * 32 + quad * 8);
#pragma unroll
            for (int mt = 0; mt < 4; ++mt) {
                f32x4 s = __builtin_amdgcn_mfma_f32_16x16x32_bf16(qf, stfrag[mt], f32x4{0.f,0.f,0.f,0.f}, 0, 0, 0);
#pragma unroll
                for (int r = 0; r < 4; ++r)
                    Es2[(nt * 16 + quad * 4 + r) * 264 + 64 * w + mt * 16 + l15] =
                        __float2bfloat16(__expf(s[r] * SCALE));
            }
        }
        __syncthreads();
        f32x4 o0 = {0.f,0.f,0.f,0.f}, o1 = o0, o2 = o0;
#pragma unroll
        for (int ks = 0; ks < 8; ++ks) {
            bf16x8 af = *(const bf16x8*)&Es2[(16 * w + l15) * 264 + ks * 32 + quad * 8];
            bf16x8 b0 = *(const bf16x8*)&sos[(l15) * 264 + ks * 32 + quad * 8];
            bf16x8 b1 = *(const bf16x8*)&sos[(16 + l15) * 264 + ks * 32 + quad * 8];
            o0 = __builtin_amdgcn_mfma_f32_16x16x32_bf16(af, b0, o0, 0, 0, 0);
            o1 = __builtin_amdgcn_mfma_f32_16x16x32_bf16(af, b1, o1, 0, 0, 0);
            o2 = __builtin_amdgcn_mfma_f32_16x16x32_bf16(af, onesf, o2, 0, 0, 0);
        }
        __syncthreads();
#pragma unroll
        for (int r = 0; r < 4; ++r) {
            float den = __shfl(o2[r], lane & 48);
            float inv = 1.f / den;
            o_t[(l15) * 68 + 16 * w + quad * 4 + r]      = o0[r] * inv;
            o_t[(16 + l15) * 68 + 16 * w + quad * 4 + r] = o1[r] * inv;
        }
        __syncthreads();
        {
            int row = t >> 3, coff = (t & 7) * 8;
            long gb = ((long)(b * 256 + h * 32 + row)) * 4096 + nbase + coff;
            int4 lp4 = *(const int4*)(lepe_cn + gb);
            const __hip_bfloat16* lp = (const __hip_bfloat16*)&lp4;
            const float* sp = &o_t[row * 68 + coff];
            float4 r0, r1;
            r0.x = sp[0] + (float)lp[0]; r0.y = sp[1] + (float)lp[1];
            r0.z = sp[2] + (float)lp[2]; r0.w = sp[3] + (float)lp[3];
            r1.x = sp[4] + (float)lp[4]; r1.y = sp[5] + (float)lp[5];
            r1.z = sp[6] + (float)lp[6]; r1.w = sp[7] + (float)lp[7];
            *(float4*)(out + gb)     = r0;
            *(float4*)(out + gb + 4) = r1;
        }
        __syncthreads();
    }
}

// ---------------------------------------------------------------------------
extern "C" void kernel_launch(void* const* d_in, const int* in_sizes, int n_in,
                              void* d_out, int out_size, void* d_ws, size_t ws_size,
                              hipStream_t stream)
{
    const float* x    = (const float*)d_in[0];
    const float* aff  = (const float*)d_in[1];
    const float* nw   = (const float*)d_in[2];
    const float* nb   = (const float*)d_in[3];
    const float* Wq   = (const float*)d_in[4];
    const float* Wk   = (const float*)d_in[5];
    const float* Wv   = (const float*)d_in[6];
    const float* Wsp  = (const float*)d_in[7];
    const float* lw   = (const float*)d_in[8];
    const float* lb   = (const float*)d_in[9];
    float* out = (float*)d_out;

    float* ws = (float*)d_ws;
    const long P = PLANE;
    __hip_bfloat16* qk_nc  = (__hip_bfloat16*)(ws);           // [b][n][512] bf16 (16.8MB)
    __hip_bfloat16* v_cn   = (__hip_bfloat16*)(ws + 4 * P);   // [b][c][n]
    __hip_bfloat16* xn_cn  = (__hip_bfloat16*)(ws + 6 * P);
    __hip_bfloat16* xn_nc  = (__hip_bfloat16*)(ws + 8 * P);
    __hip_bfloat16* lepe_cn= (__hip_bfloat16*)(ws + 10 * P);
    float* stoken_part = ws + 14 * P;                          // 32 x 65536 f32
    __hip_bfloat16* opart = (__hip_bfloat16*)(ws + 16 * P);    // 16*32*33*256 bf16
    float* tail        = ws + 16 * P + 2162688;
    __hip_bfloat16* wbf       = (__hip_bfloat16*)tail;
    __hip_bfloat16* st_md     = (__hip_bfloat16*)(tail + 262144);
    __hip_bfloat16* sout_bf   = (__hip_bfloat16*)(tail + 393216);
    float* rs_part = tail + 525312;

    // 1. fused LayerNorm (register-resident) + weight casts
    ln_fused_kernel<<<260, 512, 0, stream>>>(x, nw, nb, Wq, Wk, Wv, Wsp,
                                             xn_cn, xn_nc, wbf);
    // 2. mega1: stoken (staged K-loop) + q/k + v (one-shot, single-barrier)
    mega1_kernel<<<3200, 256, 0, stream>>>(aff, xn_cn, xn_nc, wbf,
                                           qk_nc, v_cn, stoken_part, rs_part);
    // 3. st_md with fused split-K(8) + rowsum reduce + rowscale
    stmd_kernel<<<64, 256, 0, stream>>>(stoken_part, wbf + 3 * 65536, st_md, rs_part);
    // 4. mega2: stage-1 attention partials + lepe conv in one dispatch
    mega2_kernel<<<1024, 256, 0, stream>>>(qk_nc, v_cn, st_md, opart, lw, lb, lepe_cn);
    // 5. merge -> sout_bf
    merge1_kernel<<<1024, 256, 0, stream>>>(opart, sout_bf);
    // 6. stage-2 attention + lepe add -> d_out
    stage2_mfma<<<dim3(16, 32), 256, 0, stream>>>(qk_nc, st_md, sout_bf, lepe_cn, out);
}

// Round 5
// 211.357 us; speedup vs baseline: 1.0230x; 1.0230x over previous
//
#include <hip/hip_runtime.h>
#include <hip/hip_bf16.h>

#define BATCH 4
#define CCH   256
#define HWHW  4096
#define NSP   256
#define NHEAD 8
#define SCALE 0.17677669529663689f
#define PLANE 1048576L

typedef short bf16x8 __attribute__((ext_vector_type(8)));
typedef short bf16x4 __attribute__((ext_vector_type(4)));
typedef float f32x4  __attribute__((ext_vector_type(4)));

__device__ __forceinline__ short f2bs(float f) {
    __hip_bfloat16 h = __float2bfloat16(f);
    return *(short*)&h;
}
__device__ __forceinline__ bf16x8 cvt8(float4 a, float4 b) {
    bf16x8 p;
    p[0] = f2bs(a.x); p[1] = f2bs(a.y); p[2] = f2bs(a.z); p[3] = f2bs(a.w);
    p[4] = f2bs(b.x); p[5] = f2bs(b.y); p[6] = f2bs(b.z); p[7] = f2bs(b.w);
    return p;
}
// async global->LDS, 16B per lane; LDS dest = base + lane*16 (wave-uniform base)
__device__ __forceinline__ void gll16(const __hip_bfloat16* g, __hip_bfloat16* l) {
    __builtin_amdgcn_global_load_lds(
        (const __attribute__((address_space(1))) unsigned int*)(const void*)g,
        (__attribute__((address_space(3))) unsigned int*)(void*)l,
        16, 0, 0);
}

// ---------------------------------------------------------------------------
// Fused LayerNorm -> xn_cn [b][c][n] + xn_nc [b][n][c] (bf16), register-
// resident: 512 thr/block, thread owns 8 channels x 4 pixels. Blocks 256..259: W casts.
__global__ __launch_bounds__(512)
void ln_fused_kernel(const float* __restrict__ x, const float* __restrict__ w,
                     const float* __restrict__ bb,
                     const float* __restrict__ Wq, const float* __restrict__ Wk,
                     const float* __restrict__ Wv, const float* __restrict__ Wsp,
                     __hip_bfloat16* __restrict__ xn_cn,
                     __hip_bfloat16* __restrict__ xn_nc,
                     __hip_bfloat16* __restrict__ wbf)
{
    __shared__ float ps[32][64], pss[32][64];
    __shared__ float mus[64], rstds[64];
    __shared__ float wls[256], bls[256];
    int blk = blockIdx.x;
    int t = threadIdx.x;
    if (blk >= 256) {                        // weight casts
        int sel = blk - 256;
        const float* src = (sel == 0) ? Wq : (sel == 1) ? Wk : (sel == 2) ? Wv : Wsp;
        __hip_bfloat16* dst = wbf + sel * 65536;
        for (int i = t * 4; i < 65536; i += 2048) {
            float4 f = *(const float4*)(src + i);
            __hip_bfloat16 p[4];
            p[0] = __float2bfloat16(f.x); p[1] = __float2bfloat16(f.y);
            p[2] = __float2bfloat16(f.z); p[3] = __float2bfloat16(f.w);
            *(int2*)(dst + i) = *(int2*)p;
        }
        return;
    }
    int b = blk >> 6;
    int n0 = (blk & 63) * 64;
    int pg = t & 15;                         // pixel group: 4 pixels
    int cq = t >> 4;                         // channel group: 8 channels
    if (t < 256) { wls[t] = w[t]; bls[t] = bb[t]; }

    const float* xp = x + ((long)(b * CCH + cq * 8)) * HWHW + n0 + pg * 4;
    float4 v[8];
#pragma unroll
    for (int i = 0; i < 8; ++i) v[i] = *(const float4*)(xp + (long)i * HWHW);
    float4 s = {0.f,0.f,0.f,0.f}, ss = {0.f,0.f,0.f,0.f};
#pragma unroll
    for (int i = 0; i < 8; ++i) {
        s.x += v[i].x; s.y += v[i].y; s.z += v[i].z; s.w += v[i].w;
        ss.x += v[i].x * v[i].x; ss.y += v[i].y * v[i].y;
        ss.z += v[i].z * v[i].z; ss.w += v[i].w * v[i].w;
    }
    *(float4*)&ps[cq][pg * 4]  = s;
    *(float4*)&pss[cq][pg * 4] = ss;
    __syncthreads();
    if (t < 64) {
        float S = 0.f, SS = 0.f;
#pragma unroll
        for (int q = 0; q < 32; ++q) { S += ps[q][t]; SS += pss[q][t]; }
        float mu = S * (1.f / 256.f);
        float var = SS * (1.f / 256.f) - mu * mu;
        mus[t] = mu; rstds[t] = rsqrtf(var + 1e-6f);
    }
    __syncthreads();
    float4 mu4 = *(float4*)&mus[pg * 4];
    float4 rs4 = *(float4*)&rstds[pg * 4];

    bf16x8 pk[4];                            // [pixel j][channel i]
#pragma unroll
    for (int i = 0; i < 8; ++i) {
        int c = cq * 8 + i;
        float wc = wls[c], bc = bls[c];
        short h0 = f2bs((v[i].x - mu4.x) * rs4.x * wc + bc);
        short h1 = f2bs((v[i].y - mu4.y) * rs4.y * wc + bc);
        short h2 = f2bs((v[i].z - mu4.z) * rs4.z * wc + bc);
        short h3 = f2bs((v[i].w - mu4.w) * rs4.w * wc + bc);
        pk[0][i] = h0; pk[1][i] = h1; pk[2][i] = h2; pk[3][i] = h3;
        bf16x4 q; q[0] = h0; q[1] = h1; q[2] = h2; q[3] = h3;
        *(bf16x4*)(xn_cn + ((long)(b * CCH + c)) * HWHW + n0 + pg * 4) = q;
    }
#pragma unroll
    for (int j = 0; j < 4; ++j)
        *(bf16x8*)(xn_nc + ((long)b * HWHW + n0 + pg * 4 + j) * CCH + cq * 8) = pk[j];
}

// ---------------------------------------------------------------------------
// K=256 one-shot GEMM: stage full A-tile (64x256 bf16 = 32KB) into LDS once
// (8 gll16/wave), ONE barrier, then 32 MFMAs/wave with B fragments read
// directly from global (L2/L3-resident operands). Zero K-loop barriers.
__device__ __forceinline__ void gemm_k256_oneshot(
    const __hip_bfloat16* __restrict__ A, const __hip_bfloat16* __restrict__ B,
    __hip_bfloat16* __restrict__ C, int bx, int by, int bz,
    int N, long aStrideZ, long bStrideZ, long cStrideZ,
    __hip_bfloat16* __restrict__ Asm)
{
    const int K = 256;
    const int t = threadIdx.x, lane = t & 63, w = t >> 6;
    const int l15 = lane & 15, quad = lane >> 4;
    const int Mt = by * 64, Nt = bx * 64;
    const __hip_bfloat16* aSrc = A + (long)bz * aStrideZ
        + (long)(Mt + w * 16 + l15) * K + quad * 8;
#pragma unroll
    for (int p = 0; p < 8; ++p)
        gll16(aSrc + p * 32, Asm + ((w * 8 + p) << 9));

    const int wm = (w & 1) * 2, wn = (w >> 1) * 2;
    const __hip_bfloat16* b0p = B + (long)bz * bStrideZ
        + (long)(Nt + wn * 16 + l15) * K + quad * 8;
    const __hip_bfloat16* b1p = b0p + 16 * K;
    f32x4 acc00 = {0.f,0.f,0.f,0.f}, acc01 = acc00, acc10 = acc00, acc11 = acc00;
    __syncthreads();                          // single drain: A tile ready
#pragma unroll
    for (int s = 0; s < 8; ++s) {
        bf16x8 a0 = *(const bf16x8*)&Asm[((wm * 8 + s) << 9) + lane * 8];
        bf16x8 a1 = *(const bf16x8*)&Asm[(((wm + 1) * 8 + s) << 9) + lane * 8];
        bf16x8 b0 = *(const bf16x8*)(b0p + s * 32);
        bf16x8 b1 = *(const bf16x8*)(b1p + s * 32);
        acc00 = __builtin_amdgcn_mfma_f32_16x16x32_bf16(a0, b0, acc00, 0, 0, 0);
        acc01 = __builtin_amdgcn_mfma_f32_16x16x32_bf16(a0, b1, acc01, 0, 0, 0);
        acc10 = __builtin_amdgcn_mfma_f32_16x16x32_bf16(a1, b0, acc10, 0, 0, 0);
        acc11 = __builtin_amdgcn_mfma_f32_16x16x32_bf16(a1, b1, acc11, 0, 0, 0);
    }
    f32x4 accs[2][2] = {{acc00, acc01}, {acc10, acc11}};
#pragma unroll
    for (int i = 0; i < 2; ++i)
#pragma unroll
        for (int j = 0; j < 2; ++j)
#pragma unroll
            for (int r = 0; r < 4; ++r) {
                int m = Mt + (wm + i) * 16 + quad * 4 + r;
                int n = Nt + (wn + j) * 16 + l15;
                C[(long)bz * cStrideZ + (long)m * N + n] =
                    __float2bfloat16(accs[i][j][r]);
            }
}

// ---------------------------------------------------------------------------
// bf16 MFMA NT GEMM body, BK=64 (for large-K / fp32-A cases).
// ASTAGE: 1 = A fp32 reg-convert (prefetched);
//         2 = A = sum of 8 fp32 planes (stride 65536) + fused rowscale (rsl).
// ROWSUM: emit rsPart[z*256+m].  NTL: N-tiles per block.
template <int OUTK, int ASTAGE, bool ROWSUM, int NTL>
__device__ __forceinline__ void gemm_body(
    const void* __restrict__ Av, const __hip_bfloat16* __restrict__ B,
    void* __restrict__ Cptr, int bx, int by, int bz,
    int N, int K, int kChunk, int kShift,
    long aStrideZ, long bStrideZ, long cStrideZ,
    float* __restrict__ rsPart,
    __hip_bfloat16* __restrict__ Asm, __hip_bfloat16* __restrict__ Bsm,
    float* __restrict__ rsl)
{
    int z = bz;
    int b = z >> kShift;
    int ch = z & ((1 << kShift) - 1);
    int t = threadIdx.x;
    int lane = t & 63, w = t >> 6;
    int l15 = lane & 15, quad = lane >> 4;
    int Mt = by * 64, Nt = bx * 64 * NTL;

    if (ASTAGE == 2 && t < 64) {             // fused rowsum reduce (8 chunks)
        float s = 0.f;
#pragma unroll
        for (int pl = 0; pl < 8; ++pl) s += rsPart[((b * 8 + pl) << 8) + Mt + t];
        rsl[t] = s;
    }

    long aOff = (long)b * aStrideZ + (long)ch * kChunk
        + (long)(Mt + w * 16 + l15) * K + quad * 8;
    const float* aSrcF = (const float*)Av + aOff;
    const __hip_bfloat16* bSrc = B + (long)b * bStrideZ + (long)ch * kChunk
        + (long)(Nt + w * 16 + l15) * K + quad * 8;

    f32x4 acc[NTL][2][2];
#pragma unroll
    for (int nt = 0; nt < NTL; ++nt)
#pragma unroll
        for (int i = 0; i < 2; ++i)
#pragma unroll
            for (int j = 0; j < 2; ++j) acc[nt][i][j] = f32x4{0.f,0.f,0.f,0.f};
    f32x4 rs0 = {0.f,0.f,0.f,0.f}, rs1 = rs0;
    bf16x8 onesf;
    { short o = (l15 == 0) ? (short)0x3F80 : (short)0;
      onesf = bf16x8{o, o, o, o, o, o, o, o}; }
    int wm = (w & 1) * 2, wn = (w >> 1) * 2;

    float4 pf0, pf1, pf2, pf3;
    if (ASTAGE == 1) {
        pf0 = *(const float4*)(aSrcF);      pf1 = *(const float4*)(aSrcF + 4);
        pf2 = *(const float4*)(aSrcF + 32); pf3 = *(const float4*)(aSrcF + 36);
    }

    const bf16x8* AsmU = (const bf16x8*)Asm;
    const bf16x8* BsmU = (const bf16x8*)Bsm;

    for (int k0 = 0; k0 < kChunk; k0 += 64) {
        // ---- stage A ----
        if (ASTAGE == 1) {
            *(bf16x8*)&Asm[t * 8]        = cvt8(pf0, pf1);
            *(bf16x8*)&Asm[2048 + t * 8] = cvt8(pf2, pf3);
        } else {                              // 8-plane fp32 sum
#pragma unroll
            for (int kh = 0; kh < 2; ++kh) {
                float4 s0 = {0.f,0.f,0.f,0.f}, s1 = {0.f,0.f,0.f,0.f};
#pragma unroll
                for (int pl = 0; pl < 8; ++pl) {
                    const float* p = aSrcF + (long)pl * 65536 + k0 + kh * 32;
                    float4 u0 = *(const float4*)p, u1 = *(const float4*)(p + 4);
                    s0.x += u0.x; s0.y += u0.y; s0.z += u0.z; s0.w += u0.w;
                    s1.x += u1.x; s1.y += u1.y; s1.z += u1.z; s1.w += u1.w;
                }
                *(bf16x8*)&Asm[kh * 2048 + t * 8] = cvt8(s0, s1);
            }
        }
        // ---- stage B (bf16, async direct-to-LDS) ----
#pragma unroll
        for (int nt = 0; nt < NTL; ++nt) {
            gll16(bSrc + (long)nt * 64 * K + k0,      Bsm + nt * 4096 + w * 512);
            gll16(bSrc + (long)nt * 64 * K + k0 + 32, Bsm + nt * 4096 + 2048 + w * 512);
        }
        __syncthreads();
        if (ASTAGE == 1 && k0 + 64 < kChunk) {   // prefetch next A chunk
            const float* nx = aSrcF + k0 + 64;
            pf0 = *(const float4*)nx;        pf1 = *(const float4*)(nx + 4);
            pf2 = *(const float4*)(nx + 32); pf3 = *(const float4*)(nx + 36);
        }
        // ---- MFMA ----
#pragma unroll
        for (int kh = 0; kh < 2; ++kh) {
            bf16x8 a0 = AsmU[kh * 256 + wm * 64 + lane];
            bf16x8 a1 = AsmU[kh * 256 + (wm + 1) * 64 + lane];
            if (ROWSUM) {
                rs0 = __builtin_amdgcn_mfma_f32_16x16x32_bf16(a0, onesf, rs0, 0, 0, 0);
                rs1 = __builtin_amdgcn_mfma_f32_16x16x32_bf16(a1, onesf, rs1, 0, 0, 0);
            }
#pragma unroll
            for (int nt = 0; nt < NTL; ++nt) {
                bf16x8 b0 = BsmU[nt * 512 + kh * 256 + wn * 64 + lane];
                bf16x8 b1 = BsmU[nt * 512 + kh * 256 + (wn + 1) * 64 + lane];
                acc[nt][0][0] = __builtin_amdgcn_mfma_f32_16x16x32_bf16(a0, b0, acc[nt][0][0], 0, 0, 0);
                acc[nt][0][1] = __builtin_amdgcn_mfma_f32_16x16x32_bf16(a0, b1, acc[nt][0][1], 0, 0, 0);
                acc[nt][1][0] = __builtin_amdgcn_mfma_f32_16x16x32_bf16(a1, b0, acc[nt][1][0], 0, 0, 0);
                acc[nt][1][1] = __builtin_amdgcn_mfma_f32_16x16x32_bf16(a1, b1, acc[nt][1][1], 0, 0, 0);
            }
        }
        __syncthreads();
    }
    if (ROWSUM && bx == 0 && (w >> 1) == 0 && l15 == 0) {
#pragma unroll
        for (int r = 0; r < 4; ++r) {
            rsPart[(long)z * 256 + Mt + wm * 16 + quad * 4 + r]       = rs0[r];
            rsPart[(long)z * 256 + Mt + (wm + 1) * 16 + quad * 4 + r] = rs1[r];
        }
    }
#pragma unroll
    for (int nt = 0; nt < NTL; ++nt)
#pragma unroll
        for (int i = 0; i < 2; ++i)
#pragma unroll
            for (int j = 0; j < 2; ++j)
#pragma unroll
                for (int r = 0; r < 4; ++r) {
                    int m = Mt + (wm + i) * 16 + quad * 4 + r;
                    int n = Nt + nt * 64 + (wn + j) * 16 + l15;
                    float val = acc[nt][i][j][r];
                    if (ASTAGE == 2) val /= (rsl[m - Mt] + 1e-16f);
                    long off = (long)z * cStrideZ + (long)m * N + n;
                    if (OUTK == 0) ((float*)Cptr)[off] = val;
                    else ((__hip_bfloat16*)Cptr)[off] = __float2bfloat16(val);
                }
}

// mega1: stoken partials [0,128) NTL=4 | q+k one-shot [128,2176) | v one-shot [2176,3200)
__global__ __launch_bounds__(256, 4)
void mega1_kernel(const float* __restrict__ aff,
                  const __hip_bfloat16* __restrict__ xn_cn,
                  const __hip_bfloat16* __restrict__ xn_nc,
                  const __hip_bfloat16* __restrict__ wbf,
                  __hip_bfloat16* __restrict__ qk_nc,
                  __hip_bfloat16* __restrict__ v_cn,
                  float* __restrict__ stoken_part,
                  float* __restrict__ rs_part)
{
    __shared__ __align__(16) char smem[40960];
    __hip_bfloat16* Asm = (__hip_bfloat16*)smem;            // stoken: 8KB
    __hip_bfloat16* Bsm = (__hip_bfloat16*)(smem + 8192);   // stoken: 32KB
    __hip_bfloat16* Aos = (__hip_bfloat16*)smem;            // one-shot: 32KB
    int blk = blockIdx.x;
    if (blk < 128) {          // stoken partials (longest path first)
        int i = blk;
        gemm_body<0, 1, true, 4>(aff, xn_cn, stoken_part,
            0, i & 3, i >> 2, 256, 4096, 512, 3,
            PLANE, PLANE, 65536L, rs_part, Asm, Bsm, nullptr);
    } else if (blk < 2176) {  // fused q+k: A=xn_nc rows, B=weights (direct)
        int i = blk - 128;
        gemm_k256_oneshot(xn_nc, wbf, qk_nc,
            i & 7, (i >> 3) & 63, i >> 9, 512, PLANE, 0L, 2 * PLANE, Aos);
    } else {                  // v_cn: A=Wv rows, B=xn_nc rows (direct)
        int i = blk - 2176;
        gemm_k256_oneshot(wbf + 2 * 65536, xn_nc, v_cn,
            i & 63, (i >> 6) & 3, i >> 8, 4096, 0L, PLANE, PLANE, Aos);
    }
}

// st_md = (sum_ch stoken_part)·Wsp / (rowsum+eps)  — fused split-K reduce
__global__ __launch_bounds__(256)
void stmd_kernel(const float* __restrict__ part,
                 const __hip_bfloat16* __restrict__ wsp,
                 __hip_bfloat16* __restrict__ st_md,
                 float* __restrict__ rs_part)
{
    __shared__ __hip_bfloat16 Asm[4096];
    __shared__ __hip_bfloat16 Bsm[4096];
    __shared__ float rsl[64];
    int i = blockIdx.x;
    gemm_body<1, 2, false, 1>(part, wsp, st_md,
        i & 3, (i >> 2) & 3, i >> 4, 256, 256, 256, 0,
        524288L, 0L, 65536L, rs_part, Asm, Bsm, rsl);
}

// ---------------------------------------------------------------------------
// Stage-1 MFMA attention partials (device fn; smem carved by mega2).
// v/kf operands software-pipelined one sub ahead into registers: after the
// prologue, no global-load latency remains inside the sub loop.
__device__ __forceinline__
void stage1_dev(char* smem, int chunk, int bh,
                const __hip_bfloat16* __restrict__ qk_nc,
                const __hip_bfloat16* __restrict__ v_cn,
                const __hip_bfloat16* __restrict__ st_md,
                __hip_bfloat16* __restrict__ opart)
{
    __hip_bfloat16* Es  = (__hip_bfloat16*)smem;            // 256*72*2 = 36864
    __hip_bfloat16* sts = (__hip_bfloat16*)(smem + 36864);  // 256*40*2 = 20480
    const int b = bh >> 3, h = bh & 7;
    const int t = threadIdx.x, lane = t & 63, w = t >> 6;
    const int l15 = lane & 15, quad = lane >> 4;
    const int n0 = chunk * 256;

    {
        const int4* src = (const int4*)(st_md + ((long)(b * 256 + t)) * 256 + h * 32);
        int4* dst = (int4*)&sts[t * 40];
        dst[0] = src[0]; dst[1] = src[1]; dst[2] = src[2]; dst[3] = src[3];
    }
    // prefetch sub-0 operands while sts staging is in flight
    const __hip_bfloat16* kfp = qk_nc + ((long)b * 4096 + n0 + 16 * w + l15) * 512 + 256 + h * 32 + quad * 8;
    const __hip_bfloat16* vp0 = v_cn + ((long)(b * 256 + h * 32 + l15)) * 4096 + n0 + quad * 8;
    const __hip_bfloat16* vp1 = vp0 + 16 * 4096;
    bf16x8 kfs[4], vv[4][4];
    kfs[0]   = *(const bf16x8*)(kfp);
    vv[0][0] = *(const bf16x8*)(vp0);
    vv[0][1] = *(const bf16x8*)(vp1);
    vv[0][2] = *(const bf16x8*)(vp0 + 32);
    vv[0][3] = *(const bf16x8*)(vp1 + 32);
    __syncthreads();
    bf16x8 afrag[16];
#pragma unroll
    for (int mt = 0; mt < 16; ++mt)
        afrag[mt] = *(const bf16x8*)&sts[(mt * 16 + l15) * 40 + quad * 8];
    bf16x8 onesf;
    { short o = (l15 == 0) ? (short)0x3F80 : (short)0;
      onesf = bf16x8{o, o, o, o, o, o, o, o}; }

    f32x4 occ[4][3];
#pragma unroll
    for (int i = 0; i < 4; ++i)
#pragma unroll
        for (int j = 0; j < 3; ++j) occ[i][j] = f32x4{0.f,0.f,0.f,0.f};

#pragma unroll
    for (int sub = 0; sub < 4; ++sub) {
#pragma unroll
        for (int mt = 0; mt < 16; ++mt) {
            f32x4 s = __builtin_amdgcn_mfma_f32_16x16x32_bf16(afrag[mt], kfs[sub], f32x4{0.f,0.f,0.f,0.f}, 0, 0, 0);
#pragma unroll
            for (int r = 0; r < 4; ++r)
                Es[(mt * 16 + quad * 4 + r) * 72 + 16 * w + l15] =
                    __float2bfloat16(__expf(s[r] * SCALE));
        }
        if (sub < 3) {                        // prefetch sub+1 (crosses barrier)
            kfs[sub + 1]   = *(const bf16x8*)(kfp + (long)(sub + 1) * 64 * 512);
            vv[sub + 1][0] = *(const bf16x8*)(vp0 + (sub + 1) * 64);
            vv[sub + 1][1] = *(const bf16x8*)(vp1 + (sub + 1) * 64);
            vv[sub + 1][2] = *(const bf16x8*)(vp0 + (sub + 1) * 64 + 32);
            vv[sub + 1][3] = *(const bf16x8*)(vp1 + (sub + 1) * 64 + 32);
        }
        __syncthreads();
#pragma unroll
        for (int ks = 0; ks < 2; ++ks) {
            bf16x8 bf0 = vv[sub][2 * ks + 0];
            bf16x8 bf1 = vv[sub][2 * ks + 1];
#pragma unroll
            for (int mi = 0; mi < 4; ++mi) {
                bf16x8 af = *(const bf16x8*)&Es[(64 * w + mi * 16 + l15) * 72 + ks * 32 + quad * 8];
                occ[mi][0] = __builtin_amdgcn_mfma_f32_16x16x32_bf16(af, bf0, occ[mi][0], 0, 0, 0);
                occ[mi][1] = __builtin_amdgcn_mfma_f32_16x16x32_bf16(af, bf1, occ[mi][1], 0, 0, 0);
                occ[mi][2] = __builtin_amdgcn_mfma_f32_16x16x32_bf16(af, onesf, occ[mi][2], 0, 0, 0);
            }
        }
        __syncthreads();
    }
    // transpose partials through LDS (Es dead): tb[col][m], pitch 264 bf16
    __hip_bfloat16* tb = Es;
#pragma unroll
    for (int mi = 0; mi < 4; ++mi)
#pragma unroll
        for (int jt = 0; jt < 3; ++jt) {
            if (jt == 2 && l15 != 0) continue;
            int col = jt * 16 + l15;
#pragma unroll
            for (int r = 0; r < 4; ++r) {
                int m = 64 * w + mi * 16 + quad * 4 + r;
                tb[col * 264 + m] = __float2bfloat16(occ[mi][jt][r]);
            }
        }
    __syncthreads();
    // coalesced global write: 33 rows x 256 bf16 = 4224 ints
    int* og = (int*)(opart) + (long)(chunk * 32 + bh) * 4224;
    const int* tbi = (const int*)tb;
#pragma unroll
    for (int i = 0; i < 17; ++i) {
        int idx = t + i * 256;
        if (idx < 4224) {
            int row = idx >> 7, off = idx & 127;
            og[idx] = tbi[row * 132 + off];
        }
    }
}

// Depthwise 3x3 conv + scramble-transpose (device fn; smem carved by mega2).
__device__ __forceinline__
void lepe_dev(char* smem, int bx, int cy, int b,
              const __hip_bfloat16* __restrict__ v_cn,
              const float* __restrict__ lw, const float* __restrict__ lb,
              __hip_bfloat16* __restrict__ lepe_cn)
{
    __hip_bfloat16* in_t    = (__hip_bfloat16*)smem;            // 32*384*2 = 24576
    __hip_bfloat16* tile_bf = (__hip_bfloat16*)(smem + 24576);  // 256*33*2 = 16896
    float* wls = (float*)(smem + 41472);                        // 288*4
    float* bls = (float*)(smem + 42624);                        // 32*4
    const int c0 = cy * 32;
    const int t = threadIdx.x;
    const int n0 = bx * 256, r0 = bx * 4;

    for (int i = t; i < 288; i += 256) wls[i] = lw[c0 * 9 + i];
    if (t < 32)  bls[t] = lb[c0 + t];
#pragma unroll
    for (int i = 0; i < 6; ++i) {
        int vi = t + i * 256;
        int ch = vi / 48;
        int off = (vi % 48) * 8;
        int g = (r0 - 1) * 64 + off;
        int4 val = {0, 0, 0, 0};
        if ((unsigned)g < 4096u)
            val = *(const int4*)(v_cn + (((long)(b * CCH + c0 + ch)) << 12) + g);
        *(int4*)&in_t[ch * 384 + off] = val;
    }
    __syncthreads();

    const int lane = t & 63, w = t >> 6;
#pragma unroll
    for (int i = 0; i < 8; ++i) {
        int ch = w * 8 + i;
        float cr[6], lf[6], rf[6];
#pragma unroll
        for (int rr = 0; rr < 6; ++rr) {
            cr[rr] = (float)in_t[ch * 384 + rr * 64 + lane];
            float lv = __shfl_up(cr[rr], 1);
            float rv = __shfl_down(cr[rr], 1);
            lf[rr] = (lane == 0) ? 0.f : lv;
            rf[rr] = (lane == 63) ? 0.f : rv;
        }
        float w0 = wls[ch*9+0], w1 = wls[ch*9+1], w2 = wls[ch*9+2];
        float w3 = wls[ch*9+3], w4 = wls[ch*9+4], w5 = wls[ch*9+5];
        float w6 = wls[ch*9+6], w7 = wls[ch*9+7], w8 = wls[ch*9+8];
        float bias = bls[ch];
#pragma unroll
        for (int r = 0; r < 4; ++r) {
            float acc = bias
                + lf[r]   * w0 + cr[r]   * w1 + rf[r]   * w2
                + lf[r+1] * w3 + cr[r+1] * w4 + rf[r+1] * w5
                + lf[r+2] * w6 + cr[r+2] * w7 + rf[r+2] * w8;
            tile_bf[(r * 64 + lane) * 33 + ch] = __float2bfloat16(acc);
        }
    }
    __syncthreads();
#pragma unroll
    for (int i = 0; i < 32; ++i) {
        int idx = t + i * 256;
        int nl = idx >> 5, cj = idx & 31;
        int sp = n0 + nl;
        lepe_cn[((long)(b * CCH + (sp >> 4)) << 12) + (nl & 15) * 256 + c0 + cj] =
            tile_bf[nl * 33 + cj];
    }
}

// mega2: stage1 [0,512) | lepe [512,1024)
__global__ __launch_bounds__(256)
void mega2_kernel(const __hip_bfloat16* __restrict__ qk_nc,
                  const __hip_bfloat16* __restrict__ v_cn,
                  const __hip_bfloat16* __restrict__ st_md,
                  __hip_bfloat16* __restrict__ opart,
                  const float* __restrict__ lw, const float* __restrict__ lb,
                  __hip_bfloat16* __restrict__ lepe_cn)
{
    __shared__ __align__(16) char smem[57344];
    int blk = blockIdx.x;
    if (blk < 512) {
        stage1_dev(smem, blk & 15, blk >> 4, qk_nc, v_cn, st_md, opart);
    } else {
        int j = blk - 512;
        lepe_dev(smem, j & 15, (j >> 4) & 7, j >> 7, v_cn, lw, lb, lepe_cn);
    }
}

// Merge stage-1 partials -> sout_bf[bh][d][m]  (coalesced bf16 reads)
__global__ __launch_bounds__(256)
void merge1_kernel(const __hip_bfloat16* __restrict__ opart, __hip_bfloat16* __restrict__ sout)
{
    int t = blockIdx.x * 256 + threadIdx.x;   // 262144
    int m = t & 255;
    int d = (t >> 8) & 31;
    int bh = t >> 13;
    float num = 0.f, den = 0.f;
    for (int ch = 0; ch < 16; ++ch) {
        long base = (long)((ch * 32 + bh) * 33) * 256 + m;
        num += (float)opart[base + (long)d * 256];
        den += (float)opart[base + 32 * 256];
    }
    sout[(long)bh * 8192 + d * 256 + m] = __float2bfloat16(num / den);
}

// ---------------------------------------------------------------------------
// Stage-2 MFMA attention + lepe add.  Writes final out[b][c][n].
// stfrag read direct from global (st_md L2-hot); qf pipelined one sub ahead.
__global__ __launch_bounds__(256)
void stage2_mfma(const __hip_bfloat16* __restrict__ qk_nc,
                 const __hip_bfloat16* __restrict__ st_md,
                 const __hip_bfloat16* __restrict__ sout_bf,
                 const __hip_bfloat16* __restrict__ lepe_cn,
                 float* __restrict__ out)
{
    __shared__ __hip_bfloat16 Es2[64 * 264];
    __shared__ __hip_bfloat16 sos[32 * 264];
    __shared__ float o_t[32 * 68];
    const int chunk = blockIdx.x, bh = blockIdx.y;
    const int b = bh >> 3, h = bh & 7;
    const int t = threadIdx.x, lane = t & 63, w = t >> 6;
    const int l15 = lane & 15, quad = lane >> 4;
    const int n0 = chunk * 256;

    {
        int row = t >> 3, seg = t & 7;
        const int4* src = (const int4*)(sout_bf + (long)bh * 8192 + row * 256 + seg * 32);
        int4* dst = (int4*)&sos[row * 264 + seg * 32];
        dst[0] = src[0]; dst[1] = src[1]; dst[2] = src[2]; dst[3] = src[3];
    }
    bf16x8 stfrag[4];
#pragma unroll
    for (int mt = 0; mt < 4; ++mt)
        stfrag[mt] = *(const bf16x8*)(st_md
            + ((long)(b * 256 + 64 * w + mt * 16 + l15)) * 256 + h * 32 + quad * 8);
    const __hip_bfloat16* qfp = qk_nc + ((long)b * 4096 + n0 + l15) * 512 + h * 32 + quad * 8;
    bf16x8 qq[4][4];
#pragma unroll
    for (int nt = 0; nt < 4; ++nt)
        qq[0][nt] = *(const bf16x8*)(qfp + (long)(nt * 16) * 512);
    bf16x8 onesf;
    { short o = (l15 == 0) ? (short)0x3F80 : (short)0;
      onesf = bf16x8{o, o, o, o, o, o, o, o}; }
    __syncthreads();

#pragma unroll
    for (int sub = 0; sub < 4; ++sub) {
        const int nbase = n0 + sub * 64;
#pragma unroll
        for (int nt = 0; nt < 4; ++nt) {
            bf16x8 qf = qq[sub][nt];
#pragma unroll
            for (int mt = 0; mt < 4; ++mt) {
                f32x4 s = __builtin_amdgcn_mfma_f32_16x16x32_bf16(qf, stfrag[mt], f32x4{0.f,0.f,0.f,0.f}, 0, 0, 0);
#pragma unroll
                for (int r = 0; r < 4; ++r)
                    Es2[(nt * 16 + quad * 4 + r) * 264 + 64 * w + mt * 16 + l15] =
                        __float2bfloat16(__expf(s[r] * SCALE));
            }
        }
        if (sub < 3) {                        // prefetch sub+1 (crosses barrier)
#pragma unroll
            for (int nt = 0; nt < 4; ++nt)
                qq[sub + 1][nt] = *(const bf16x8*)(qfp + (long)((sub + 1) * 64 + nt * 16) * 512);
        }
        __syncthreads();
        f32x4 o0 = {0.f,0.f,0.f,0.f}, o1 = o0, o2 = o0;
#pragma unroll
        for (int ks = 0; ks < 8; ++ks) {
            bf16x8 af = *(const bf16x8*)&Es2[(16 * w + l15) * 264 + ks * 32 + quad * 8];
            bf16x8 b0 = *(const bf16x8*)&sos[(l15) * 264 + ks * 32 + quad * 8];
            bf16x8 b1 = *(const bf16x8*)&sos[(16 + l15) * 264 + ks * 32 + quad * 8];
            o0 = __builtin_amdgcn_mfma_f32_16x16x32_bf16(af, b0, o0, 0, 0, 0);
            o1 = __builtin_amdgcn_mfma_f32_16x16x32_bf16(af, b1, o1, 0, 0, 0);
            o2 = __builtin_amdgcn_mfma_f32_16x16x32_bf16(af, onesf, o2, 0, 0, 0);
        }
        __syncthreads();
#pragma unroll
        for (int r = 0; r < 4; ++r) {
            float den = __shfl(o2[r], lane & 48);
            float inv = 1.f / den;
            o_t[(l15) * 68 + 16 * w + quad * 4 + r]      = o0[r] * inv;
            o_t[(16 + l15) * 68 + 16 * w + quad * 4 + r] = o1[r] * inv;
        }
        __syncthreads();
        {
            int row = t >> 3, coff = (t & 7) * 8;
            long gb = ((long)(b * 256 + h * 32 + row)) * 4096 + nbase + coff;
            int4 lp4 = *(const int4*)(lepe_cn + gb);
            const __hip_bfloat16* lp = (const __hip_bfloat16*)&lp4;
            const float* sp = &o_t[row * 68 + coff];
            float4 r0, r1;
            r0.x = sp[0] + (float)lp[0]; r0.y = sp[1] + (float)lp[1];
            r0.z = sp[2] + (float)lp[2]; r0.w = sp[3] + (float)lp[3];
            r1.x = sp[4] + (float)lp[4]; r1.y = sp[5] + (float)lp[5];
            r1.z = sp[6] + (float)lp[6]; r1.w = sp[7] + (float)lp[7];
            *(float4*)(out + gb)     = r0;
            *(float4*)(out + gb + 4) = r1;
        }
        __syncthreads();
    }
}

// ---------------------------------------------------------------------------
extern "C" void kernel_launch(void* const* d_in, const int* in_sizes, int n_in,
                              void* d_out, int out_size, void* d_ws, size_t ws_size,
                              hipStream_t stream)
{
    const float* x    = (const float*)d_in[0];
    const float* aff  = (const float*)d_in[1];
    const float* nw   = (const float*)d_in[2];
    const float* nb   = (const float*)d_in[3];
    const float* Wq   = (const float*)d_in[4];
    const float* Wk   = (const float*)d_in[5];
    const float* Wv   = (const float*)d_in[6];
    const float* Wsp  = (const float*)d_in[7];
    const float* lw   = (const float*)d_in[8];
    const float* lb   = (const float*)d_in[9];
    float* out = (float*)d_out;

    float* ws = (float*)d_ws;
    const long P = PLANE;
    __hip_bfloat16* qk_nc  = (__hip_bfloat16*)(ws);           // [b][n][512] bf16 (16.8MB)
    __hip_bfloat16* v_cn   = (__hip_bfloat16*)(ws + 4 * P);   // [b][c][n]
    __hip_bfloat16* xn_cn  = (__hip_bfloat16*)(ws + 6 * P);
    __hip_bfloat16* xn_nc  = (__hip_bfloat16*)(ws + 8 * P);
    __hip_bfloat16* lepe_cn= (__hip_bfloat16*)(ws + 10 * P);
    float* stoken_part = ws + 14 * P;                          // 32 x 65536 f32
    __hip_bfloat16* opart = (__hip_bfloat16*)(ws + 16 * P);    // 16*32*33*256 bf16
    float* tail        = ws + 16 * P + 2162688;
    __hip_bfloat16* wbf       = (__hip_bfloat16*)tail;
    __hip_bfloat16* st_md     = (__hip_bfloat16*)(tail + 262144);
    __hip_bfloat16* sout_bf   = (__hip_bfloat16*)(tail + 393216);
    float* rs_part = tail + 525312;

    // 1. fused LayerNorm (register-resident) + weight casts
    ln_fused_kernel<<<260, 512, 0, stream>>>(x, nw, nb, Wq, Wk, Wv, Wsp,
                                             xn_cn, xn_nc, wbf);
    // 2. mega1: stoken (staged K-loop) + q/k + v (one-shot, single-barrier)
    mega1_kernel<<<3200, 256, 0, stream>>>(aff, xn_cn, xn_nc, wbf,
                                           qk_nc, v_cn, stoken_part, rs_part);
    // 3. st_md with fused split-K(8) + rowsum reduce + rowscale
    stmd_kernel<<<64, 256, 0, stream>>>(stoken_part, wbf + 3 * 65536, st_md, rs_part);
    // 4. mega2: stage-1 attention partials (v/kf pipelined) + lepe conv
    mega2_kernel<<<1024, 256, 0, stream>>>(qk_nc, v_cn, st_md, opart, lw, lb, lepe_cn);
    // 5. merge -> sout_bf
    merge1_kernel<<<1024, 256, 0, stream>>>(opart, sout_bf);
    // 6. stage-2 attention (qf pipelined) + lepe add -> d_out
    stage2_mfma<<<dim3(16, 32), 256, 0, stream>>>(qk_nc, st_md, sout_bf, lepe_cn, out);
}

// Round 6
// 195.802 us; speedup vs baseline: 1.1043x; 1.0794x over previous
//
#include <hip/hip_runtime.h>
#include <hip/hip_bf16.h>

#define BATCH 4
#define CCH   256
#define HWHW  4096
#define NSP   256
#define NHEAD 8
#define SCALE 0.17677669529663689f
#define PLANE 1048576L

typedef short bf16x8 __attribute__((ext_vector_type(8)));
typedef short bf16x4 __attribute__((ext_vector_type(4)));
typedef float f32x4  __attribute__((ext_vector_type(4)));

__device__ __forceinline__ short f2bs(float f) {
    __hip_bfloat16 h = __float2bfloat16(f);
    return *(short*)&h;
}
__device__ __forceinline__ bf16x8 cvt8(float4 a, float4 b) {
    bf16x8 p;
    p[0] = f2bs(a.x); p[1] = f2bs(a.y); p[2] = f2bs(a.z); p[3] = f2bs(a.w);
    p[4] = f2bs(b.x); p[5] = f2bs(b.y); p[6] = f2bs(b.z); p[7] = f2bs(b.w);
    return p;
}
// async global->LDS, 16B per lane; LDS dest = base + lane*16 (wave-uniform base)
__device__ __forceinline__ void gll16(const __hip_bfloat16* g, __hip_bfloat16* l) {
    __builtin_amdgcn_global_load_lds(
        (const __attribute__((address_space(1))) unsigned int*)(const void*)g,
        (__attribute__((address_space(3))) unsigned int*)(void*)l,
        16, 0, 0);
}

// ---------------------------------------------------------------------------
// Fused LayerNorm -> xn_cn [b][c][n] + xn_nc [b][n][c] (bf16), register-
// resident: 512 thr/block, thread owns 8 channels x 4 pixels. Blocks 256..259: W casts.
__global__ __launch_bounds__(512)
void ln_fused_kernel(const float* __restrict__ x, const float* __restrict__ w,
                     const float* __restrict__ bb,
                     const float* __restrict__ Wq, const float* __restrict__ Wk,
                     const float* __restrict__ Wv, const float* __restrict__ Wsp,
                     __hip_bfloat16* __restrict__ xn_cn,
                     __hip_bfloat16* __restrict__ xn_nc,
                     __hip_bfloat16* __restrict__ wbf)
{
    __shared__ float ps[32][64], pss[32][64];
    __shared__ float mus[64], rstds[64];
    __shared__ float wls[256], bls[256];
    int blk = blockIdx.x;
    int t = threadIdx.x;
    if (blk >= 256) {                        // weight casts
        int sel = blk - 256;
        const float* src = (sel == 0) ? Wq : (sel == 1) ? Wk : (sel == 2) ? Wv : Wsp;
        __hip_bfloat16* dst = wbf + sel * 65536;
        for (int i = t * 4; i < 65536; i += 2048) {
            float4 f = *(const float4*)(src + i);
            __hip_bfloat16 p[4];
            p[0] = __float2bfloat16(f.x); p[1] = __float2bfloat16(f.y);
            p[2] = __float2bfloat16(f.z); p[3] = __float2bfloat16(f.w);
            *(int2*)(dst + i) = *(int2*)p;
        }
        return;
    }
    int b = blk >> 6;
    int n0 = (blk & 63) * 64;
    int pg = t & 15;                         // pixel group: 4 pixels
    int cq = t >> 4;                         // channel group: 8 channels
    if (t < 256) { wls[t] = w[t]; bls[t] = bb[t]; }

    const float* xp = x + ((long)(b * CCH + cq * 8)) * HWHW + n0 + pg * 4;
    float4 v[8];
#pragma unroll
    for (int i = 0; i < 8; ++i) v[i] = *(const float4*)(xp + (long)i * HWHW);
    float4 s = {0.f,0.f,0.f,0.f}, ss = {0.f,0.f,0.f,0.f};
#pragma unroll
    for (int i = 0; i < 8; ++i) {
        s.x += v[i].x; s.y += v[i].y; s.z += v[i].z; s.w += v[i].w;
        ss.x += v[i].x * v[i].x; ss.y += v[i].y * v[i].y;
        ss.z += v[i].z * v[i].z; ss.w += v[i].w * v[i].w;
    }
    *(float4*)&ps[cq][pg * 4]  = s;
    *(float4*)&pss[cq][pg * 4] = ss;
    __syncthreads();
    if (t < 64) {
        float S = 0.f, SS = 0.f;
#pragma unroll
        for (int q = 0; q < 32; ++q) { S += ps[q][t]; SS += pss[q][t]; }
        float mu = S * (1.f / 256.f);
        float var = SS * (1.f / 256.f) - mu * mu;
        mus[t] = mu; rstds[t] = rsqrtf(var + 1e-6f);
    }
    __syncthreads();
    float4 mu4 = *(float4*)&mus[pg * 4];
    float4 rs4 = *(float4*)&rstds[pg * 4];

    bf16x8 pk[4];                            // [pixel j][channel i]
#pragma unroll
    for (int i = 0; i < 8; ++i) {
        int c = cq * 8 + i;
        float wc = wls[c], bc = bls[c];
        short h0 = f2bs((v[i].x - mu4.x) * rs4.x * wc + bc);
        short h1 = f2bs((v[i].y - mu4.y) * rs4.y * wc + bc);
        short h2 = f2bs((v[i].z - mu4.z) * rs4.z * wc + bc);
        short h3 = f2bs((v[i].w - mu4.w) * rs4.w * wc + bc);
        pk[0][i] = h0; pk[1][i] = h1; pk[2][i] = h2; pk[3][i] = h3;
        bf16x4 q; q[0] = h0; q[1] = h1; q[2] = h2; q[3] = h3;
        *(bf16x4*)(xn_cn + ((long)(b * CCH + c)) * HWHW + n0 + pg * 4) = q;
    }
#pragma unroll
    for (int j = 0; j < 4; ++j)
        *(bf16x8*)(xn_nc + ((long)b * HWHW + n0 + pg * 4 + j) * CCH + cq * 8) = pk[j];
}

// ---------------------------------------------------------------------------
// K=256 one-shot 128x128 GEMM: stage full A-tile (128x256 bf16 = 64KB) into
// LDS once via 64 gll16 in slab layout [rowtile][kslot] (staging pattern ==
// consumption pattern -> conflict-free ds_read_b128), ONE barrier, then each
// wave computes a 64x64 quadrant: 4x4 accs = 128 MFMAs, with B fragments
// direct-from-global, one-deep register prefetch.  Bit-identical k order.
__device__ __forceinline__ void gemm_k256_128(
    const __hip_bfloat16* __restrict__ A, const __hip_bfloat16* __restrict__ B,
    __hip_bfloat16* __restrict__ C, int bx, int by, int bz,
    int N, long aStrideZ, long bStrideZ, long cStrideZ,
    __hip_bfloat16* __restrict__ Asm)
{
    const int K = 256;
    const int t = threadIdx.x, lane = t & 63, w = t >> 6;
    const int l15 = lane & 15, quad = lane >> 4;
    const int Mt = by * 128, Nt = bx * 128;
    // stage A: slab (rt,s) = rows [rt*16,rt*16+16) x k [s*32,s*32+32) = 1KB
    {
        const __hip_bfloat16* aBase = A + (long)bz * aStrideZ
            + (long)(Mt + l15) * K + quad * 8;
#pragma unroll
        for (int p = 0; p < 16; ++p) {
            const int rt = w * 2 + (p >> 3), s = p & 7;
            gll16(aBase + (long)(rt * 16) * K + s * 32, Asm + (rt * 8 + s) * 512);
        }
    }
    const int wm2 = w & 1, wn2 = w >> 1;
    const __hip_bfloat16* bBase = B + (long)bz * bStrideZ
        + (long)(Nt + wn2 * 64 + l15) * K + quad * 8;

    f32x4 acc[4][4];
#pragma unroll
    for (int mi = 0; mi < 4; ++mi)
#pragma unroll
        for (int nj = 0; nj < 4; ++nj) acc[mi][nj] = f32x4{0.f,0.f,0.f,0.f};

    bf16x8 bEv[4], bOd[4];
#pragma unroll
    for (int nj = 0; nj < 4; ++nj)
        bEv[nj] = *(const bf16x8*)(bBase + (long)(nj * 16) * K);
    __syncthreads();                          // A tile ready
#pragma unroll
    for (int sp = 0; sp < 4; ++sp) {
        const int s0 = 2 * sp, s1 = 2 * sp + 1;
#pragma unroll
        for (int nj = 0; nj < 4; ++nj)       // prefetch odd slot
            bOd[nj] = *(const bf16x8*)(bBase + (long)(nj * 16) * K + s1 * 32);
#pragma unroll
        for (int mi = 0; mi < 4; ++mi) {
            bf16x8 a = *(const bf16x8*)&Asm[((wm2 * 4 + mi) * 8 + s0) * 512 + lane * 8];
            acc[mi][0] = __builtin_amdgcn_mfma_f32_16x16x32_bf16(a, bEv[0], acc[mi][0], 0, 0, 0);
            acc[mi][1] = __builtin_amdgcn_mfma_f32_16x16x32_bf16(a, bEv[1], acc[mi][1], 0, 0, 0);
            acc[mi][2] = __builtin_amdgcn_mfma_f32_16x16x32_bf16(a, bEv[2], acc[mi][2], 0, 0, 0);
            acc[mi][3] = __builtin_amdgcn_mfma_f32_16x16x32_bf16(a, bEv[3], acc[mi][3], 0, 0, 0);
        }
        if (sp < 3) {
#pragma unroll
            for (int nj = 0; nj < 4; ++nj)   // prefetch next even slot
                bEv[nj] = *(const bf16x8*)(bBase + (long)(nj * 16) * K + (s0 + 2) * 32);
        }
#pragma unroll
        for (int mi = 0; mi < 4; ++mi) {
            bf16x8 a = *(const bf16x8*)&Asm[((wm2 * 4 + mi) * 8 + s1) * 512 + lane * 8];
            acc[mi][0] = __builtin_amdgcn_mfma_f32_16x16x32_bf16(a, bOd[0], acc[mi][0], 0, 0, 0);
            acc[mi][1] = __builtin_amdgcn_mfma_f32_16x16x32_bf16(a, bOd[1], acc[mi][1], 0, 0, 0);
            acc[mi][2] = __builtin_amdgcn_mfma_f32_16x16x32_bf16(a, bOd[2], acc[mi][2], 0, 0, 0);
            acc[mi][3] = __builtin_amdgcn_mfma_f32_16x16x32_bf16(a, bOd[3], acc[mi][3], 0, 0, 0);
        }
    }
#pragma unroll
    for (int mi = 0; mi < 4; ++mi)
#pragma unroll
        for (int nj = 0; nj < 4; ++nj)
#pragma unroll
            for (int r = 0; r < 4; ++r) {
                int m = Mt + wm2 * 64 + mi * 16 + quad * 4 + r;
                int n = Nt + wn2 * 64 + nj * 16 + l15;
                C[(long)bz * cStrideZ + (long)m * N + n] =
                    __float2bfloat16(acc[mi][nj][r]);
            }
}

// ---------------------------------------------------------------------------
// bf16 MFMA NT GEMM body, BK=64 (for large-K / fp32-A cases).
// ASTAGE: 1 = A fp32 reg-convert (prefetched);
//         2 = A = sum of 8 fp32 planes (stride 65536) + fused rowscale (rsl).
// ROWSUM: emit rsPart[z*256+m].  NTL: N-tiles per block.
template <int OUTK, int ASTAGE, bool ROWSUM, int NTL>
__device__ __forceinline__ void gemm_body(
    const void* __restrict__ Av, const __hip_bfloat16* __restrict__ B,
    void* __restrict__ Cptr, int bx, int by, int bz,
    int N, int K, int kChunk, int kShift,
    long aStrideZ, long bStrideZ, long cStrideZ,
    float* __restrict__ rsPart,
    __hip_bfloat16* __restrict__ Asm, __hip_bfloat16* __restrict__ Bsm,
    float* __restrict__ rsl)
{
    int z = bz;
    int b = z >> kShift;
    int ch = z & ((1 << kShift) - 1);
    int t = threadIdx.x;
    int lane = t & 63, w = t >> 6;
    int l15 = lane & 15, quad = lane >> 4;
    int Mt = by * 64, Nt = bx * 64 * NTL;

    if (ASTAGE == 2 && t < 64) {             // fused rowsum reduce (8 chunks)
        float s = 0.f;
#pragma unroll
        for (int pl = 0; pl < 8; ++pl) s += rsPart[((b * 8 + pl) << 8) + Mt + t];
        rsl[t] = s;
    }

    long aOff = (long)b * aStrideZ + (long)ch * kChunk
        + (long)(Mt + w * 16 + l15) * K + quad * 8;
    const float* aSrcF = (const float*)Av + aOff;
    const __hip_bfloat16* bSrc = B + (long)b * bStrideZ + (long)ch * kChunk
        + (long)(Nt + w * 16 + l15) * K + quad * 8;

    f32x4 acc[NTL][2][2];
#pragma unroll
    for (int nt = 0; nt < NTL; ++nt)
#pragma unroll
        for (int i = 0; i < 2; ++i)
#pragma unroll
            for (int j = 0; j < 2; ++j) acc[nt][i][j] = f32x4{0.f,0.f,0.f,0.f};
    f32x4 rs0 = {0.f,0.f,0.f,0.f}, rs1 = rs0;
    bf16x8 onesf;
    { short o = (l15 == 0) ? (short)0x3F80 : (short)0;
      onesf = bf16x8{o, o, o, o, o, o, o, o}; }
    int wm = (w & 1) * 2, wn = (w >> 1) * 2;

    float4 pf0, pf1, pf2, pf3;
    if (ASTAGE == 1) {
        pf0 = *(const float4*)(aSrcF);      pf1 = *(const float4*)(aSrcF + 4);
        pf2 = *(const float4*)(aSrcF + 32); pf3 = *(const float4*)(aSrcF + 36);
    }

    const bf16x8* AsmU = (const bf16x8*)Asm;
    const bf16x8* BsmU = (const bf16x8*)Bsm;

    for (int k0 = 0; k0 < kChunk; k0 += 64) {
        // ---- stage A ----
        if (ASTAGE == 1) {
            *(bf16x8*)&Asm[t * 8]        = cvt8(pf0, pf1);
            *(bf16x8*)&Asm[2048 + t * 8] = cvt8(pf2, pf3);
        } else {                              // 8-plane fp32 sum
#pragma unroll
            for (int kh = 0; kh < 2; ++kh) {
                float4 s0 = {0.f,0.f,0.f,0.f}, s1 = {0.f,0.f,0.f,0.f};
#pragma unroll
                for (int pl = 0; pl < 8; ++pl) {
                    const float* p = aSrcF + (long)pl * 65536 + k0 + kh * 32;
                    float4 u0 = *(const float4*)p, u1 = *(const float4*)(p + 4);
                    s0.x += u0.x; s0.y += u0.y; s0.z += u0.z; s0.w += u0.w;
                    s1.x += u1.x; s1.y += u1.y; s1.z += u1.z; s1.w += u1.w;
                }
                *(bf16x8*)&Asm[kh * 2048 + t * 8] = cvt8(s0, s1);
            }
        }
        // ---- stage B (bf16, async direct-to-LDS) ----
#pragma unroll
        for (int nt = 0; nt < NTL; ++nt) {
            gll16(bSrc + (long)nt * 64 * K + k0,      Bsm + nt * 4096 + w * 512);
            gll16(bSrc + (long)nt * 64 * K + k0 + 32, Bsm + nt * 4096 + 2048 + w * 512);
        }
        __syncthreads();
        if (ASTAGE == 1 && k0 + 64 < kChunk) {   // prefetch next A chunk
            const float* nx = aSrcF + k0 + 64;
            pf0 = *(const float4*)nx;        pf1 = *(const float4*)(nx + 4);
            pf2 = *(const float4*)(nx + 32); pf3 = *(const float4*)(nx + 36);
        }
        // ---- MFMA ----
#pragma unroll
        for (int kh = 0; kh < 2; ++kh) {
            bf16x8 a0 = AsmU[kh * 256 + wm * 64 + lane];
            bf16x8 a1 = AsmU[kh * 256 + (wm + 1) * 64 + lane];
            if (ROWSUM) {
                rs0 = __builtin_amdgcn_mfma_f32_16x16x32_bf16(a0, onesf, rs0, 0, 0, 0);
                rs1 = __builtin_amdgcn_mfma_f32_16x16x32_bf16(a1, onesf, rs1, 0, 0, 0);
            }
#pragma unroll
            for (int nt = 0; nt < NTL; ++nt) {
                bf16x8 b0 = BsmU[nt * 512 + kh * 256 + wn * 64 + lane];
                bf16x8 b1 = BsmU[nt * 512 + kh * 256 + (wn + 1) * 64 + lane];
                acc[nt][0][0] = __builtin_amdgcn_mfma_f32_16x16x32_bf16(a0, b0, acc[nt][0][0], 0, 0, 0);
                acc[nt][0][1] = __builtin_amdgcn_mfma_f32_16x16x32_bf16(a0, b1, acc[nt][0][1], 0, 0, 0);
                acc[nt][1][0] = __builtin_amdgcn_mfma_f32_16x16x32_bf16(a1, b0, acc[nt][1][0], 0, 0, 0);
                acc[nt][1][1] = __builtin_amdgcn_mfma_f32_16x16x32_bf16(a1, b1, acc[nt][1][1], 0, 0, 0);
            }
        }
        __syncthreads();
    }
    if (ROWSUM && bx == 0 && (w >> 1) == 0 && l15 == 0) {
#pragma unroll
        for (int r = 0; r < 4; ++r) {
            rsPart[(long)z * 256 + Mt + wm * 16 + quad * 4 + r]       = rs0[r];
            rsPart[(long)z * 256 + Mt + (wm + 1) * 16 + quad * 4 + r] = rs1[r];
        }
    }
#pragma unroll
    for (int nt = 0; nt < NTL; ++nt)
#pragma unroll
        for (int i = 0; i < 2; ++i)
#pragma unroll
            for (int j = 0; j < 2; ++j)
#pragma unroll
                for (int r = 0; r < 4; ++r) {
                    int m = Mt + (wm + i) * 16 + quad * 4 + r;
                    int n = Nt + nt * 64 + (wn + j) * 16 + l15;
                    float val = acc[nt][i][j][r];
                    if (ASTAGE == 2) val /= (rsl[m - Mt] + 1e-16f);
                    long off = (long)z * cStrideZ + (long)m * N + n;
                    if (OUTK == 0) ((float*)Cptr)[off] = val;
                    else ((__hip_bfloat16*)Cptr)[off] = __float2bfloat16(val);
                }
}

// mega1: stoken [0,128) | q+k 128-tile [128,640) | v 128-tile [640,896)
// Index decodes ordered so blocks sharing an operand tile are 8 apart in
// dispatch index (same XCD L2) — T1 colocation.
__global__ __launch_bounds__(256, 2)
void mega1_kernel(const float* __restrict__ aff,
                  const __hip_bfloat16* __restrict__ xn_cn,
                  const __hip_bfloat16* __restrict__ xn_nc,
                  const __hip_bfloat16* __restrict__ wbf,
                  __hip_bfloat16* __restrict__ qk_nc,
                  __hip_bfloat16* __restrict__ v_cn,
                  float* __restrict__ stoken_part,
                  float* __restrict__ rs_part)
{
    __shared__ __align__(16) char smem[65536];
    __hip_bfloat16* Asm = (__hip_bfloat16*)smem;            // stoken: 8KB
    __hip_bfloat16* Bsm = (__hip_bfloat16*)(smem + 8192);   // stoken: 32KB
    __hip_bfloat16* A128 = (__hip_bfloat16*)smem;           // 128-tile: 64KB
    int blk = blockIdx.x;
    if (blk < 128) {          // stoken partials; same-z (shared B) 32 apart
        int i = blk;
        gemm_body<0, 1, true, 4>(aff, xn_cn, stoken_part,
            0, i >> 5, i & 31, 256, 4096, 512, 3,
            PLANE, PLANE, 65536L, rs_part, Asm, Bsm, nullptr);
    } else if (blk < 640) {   // fused q+k: A=xn_nc tile shared by bx=0..3 (128 apart)
        int i = blk - 128;
        int bx = i >> 7, rem = i & 127;
        gemm_k256_128(xn_nc, wbf, qk_nc,
            bx, rem >> 2, rem & 3, 512, PLANE, 0L, 2 * PLANE, A128);
    } else {                  // v_cn: B=xn_nc tile shared by by=0..1 (128 apart)
        int i = blk - 640;
        int by = i >> 7, rem = i & 127;
        gemm_k256_128(wbf + 2 * 65536, xn_nc, v_cn,
            rem >> 2, by, rem & 3, 4096, 0L, PLANE, PLANE, A128);
    }
}

// st_md = (sum_ch stoken_part)·Wsp / (rowsum+eps)  — fused split-K reduce
__global__ __launch_bounds__(256)
void stmd_kernel(const float* __restrict__ part,
                 const __hip_bfloat16* __restrict__ wsp,
                 __hip_bfloat16* __restrict__ st_md,
                 float* __restrict__ rs_part)
{
    __shared__ __hip_bfloat16 Asm[4096];
    __shared__ __hip_bfloat16 Bsm[4096];
    __shared__ float rsl[64];
    int i = blockIdx.x;
    gemm_body<1, 2, false, 1>(part, wsp, st_md,
        i & 3, (i >> 2) & 3, i >> 4, 256, 256, 256, 0,
        524288L, 0L, 65536L, rs_part, Asm, Bsm, rsl);
}

// ---------------------------------------------------------------------------
// Stage-1 MFMA attention partials (device fn; smem carved by mega2).
// v/kf operands software-pipelined one sub ahead into registers.
__device__ __forceinline__
void stage1_dev(char* smem, int chunk, int bh,
                const __hip_bfloat16* __restrict__ qk_nc,
                const __hip_bfloat16* __restrict__ v_cn,
                const __hip_bfloat16* __restrict__ st_md,
                __hip_bfloat16* __restrict__ opart)
{
    __hip_bfloat16* Es  = (__hip_bfloat16*)smem;            // 256*72*2 = 36864
    __hip_bfloat16* sts = (__hip_bfloat16*)(smem + 36864);  // 256*40*2 = 20480
    const int b = bh >> 3, h = bh & 7;
    const int t = threadIdx.x, lane = t & 63, w = t >> 6;
    const int l15 = lane & 15, quad = lane >> 4;
    const int n0 = chunk * 256;

    {
        const int4* src = (const int4*)(st_md + ((long)(b * 256 + t)) * 256 + h * 32);
        int4* dst = (int4*)&sts[t * 40];
        dst[0] = src[0]; dst[1] = src[1]; dst[2] = src[2]; dst[3] = src[3];
    }
    // prefetch sub-0 operands while sts staging is in flight
    const __hip_bfloat16* kfp = qk_nc + ((long)b * 4096 + n0 + 16 * w + l15) * 512 + 256 + h * 32 + quad * 8;
    const __hip_bfloat16* vp0 = v_cn + ((long)(b * 256 + h * 32 + l15)) * 4096 + n0 + quad * 8;
    const __hip_bfloat16* vp1 = vp0 + 16 * 4096;
    bf16x8 kfs[4], vv[4][4];
    kfs[0]   = *(const bf16x8*)(kfp);
    vv[0][0] = *(const bf16x8*)(vp0);
    vv[0][1] = *(const bf16x8*)(vp1);
    vv[0][2] = *(const bf16x8*)(vp0 + 32);
    vv[0][3] = *(const bf16x8*)(vp1 + 32);
    __syncthreads();
    bf16x8 afrag[16];
#pragma unroll
    for (int mt = 0; mt < 16; ++mt)
        afrag[mt] = *(const bf16x8*)&sts[(mt * 16 + l15) * 40 + quad * 8];
    bf16x8 onesf;
    { short o = (l15 == 0) ? (short)0x3F80 : (short)0;
      onesf = bf16x8{o, o, o, o, o, o, o, o}; }

    f32x4 occ[4][3];
#pragma unroll
    for (int i = 0; i < 4; ++i)
#pragma unroll
        for (int j = 0; j < 3; ++j) occ[i][j] = f32x4{0.f,0.f,0.f,0.f};

#pragma unroll
    for (int sub = 0; sub < 4; ++sub) {
#pragma unroll
        for (int mt = 0; mt < 16; ++mt) {
            f32x4 s = __builtin_amdgcn_mfma_f32_16x16x32_bf16(afrag[mt], kfs[sub], f32x4{0.f,0.f,0.f,0.f}, 0, 0, 0);
#pragma unroll
            for (int r = 0; r < 4; ++r)
                Es[(mt * 16 + quad * 4 + r) * 72 + 16 * w + l15] =
                    __float2bfloat16(__expf(s[r] * SCALE));
        }
        if (sub < 3) {                        // prefetch sub+1 (crosses barrier)
            kfs[sub + 1]   = *(const bf16x8*)(kfp + (long)(sub + 1) * 64 * 512);
            vv[sub + 1][0] = *(const bf16x8*)(vp0 + (sub + 1) * 64);
            vv[sub + 1][1] = *(const bf16x8*)(vp1 + (sub + 1) * 64);
            vv[sub + 1][2] = *(const bf16x8*)(vp0 + (sub + 1) * 64 + 32);
            vv[sub + 1][3] = *(const bf16x8*)(vp1 + (sub + 1) * 64 + 32);
        }
        __syncthreads();
#pragma unroll
        for (int ks = 0; ks < 2; ++ks) {
            bf16x8 bf0 = vv[sub][2 * ks + 0];
            bf16x8 bf1 = vv[sub][2 * ks + 1];
#pragma unroll
            for (int mi = 0; mi < 4; ++mi) {
                bf16x8 af = *(const bf16x8*)&Es[(64 * w + mi * 16 + l15) * 72 + ks * 32 + quad * 8];
                occ[mi][0] = __builtin_amdgcn_mfma_f32_16x16x32_bf16(af, bf0, occ[mi][0], 0, 0, 0);
                occ[mi][1] = __builtin_amdgcn_mfma_f32_16x16x32_bf16(af, bf1, occ[mi][1], 0, 0, 0);
                occ[mi][2] = __builtin_amdgcn_mfma_f32_16x16x32_bf16(af, onesf, occ[mi][2], 0, 0, 0);
            }
        }
        __syncthreads();
    }
    // transpose partials through LDS (Es dead): tb[col][m], pitch 264 bf16
    __hip_bfloat16* tb = Es;
#pragma unroll
    for (int mi = 0; mi < 4; ++mi)
#pragma unroll
        for (int jt = 0; jt < 3; ++jt) {
            if (jt == 2 && l15 != 0) continue;
            int col = jt * 16 + l15;
#pragma unroll
            for (int r = 0; r < 4; ++r) {
                int m = 64 * w + mi * 16 + quad * 4 + r;
                tb[col * 264 + m] = __float2bfloat16(occ[mi][jt][r]);
            }
        }
    __syncthreads();
    // coalesced global write: 33 rows x 256 bf16 = 4224 ints
    int* og = (int*)(opart) + (long)(chunk * 32 + bh) * 4224;
    const int* tbi = (const int*)tb;
#pragma unroll
    for (int i = 0; i < 17; ++i) {
        int idx = t + i * 256;
        if (idx < 4224) {
            int row = idx >> 7, off = idx & 127;
            og[idx] = tbi[row * 132 + off];
        }
    }
}

// Depthwise 3x3 conv + scramble-transpose (device fn; smem carved by mega2).
__device__ __forceinline__
void lepe_dev(char* smem, int bx, int cy, int b,
              const __hip_bfloat16* __restrict__ v_cn,
              const float* __restrict__ lw, const float* __restrict__ lb,
              __hip_bfloat16* __restrict__ lepe_cn)
{
    __hip_bfloat16* in_t    = (__hip_bfloat16*)smem;            // 32*384*2 = 24576
    __hip_bfloat16* tile_bf = (__hip_bfloat16*)(smem + 24576);  // 256*33*2 = 16896
    float* wls = (float*)(smem + 41472);                        // 288*4
    float* bls = (float*)(smem + 42624);                        // 32*4
    const int c0 = cy * 32;
    const int t = threadIdx.x;
    const int n0 = bx * 256, r0 = bx * 4;

    for (int i = t; i < 288; i += 256) wls[i] = lw[c0 * 9 + i];
    if (t < 32)  bls[t] = lb[c0 + t];
#pragma unroll
    for (int i = 0; i < 6; ++i) {
        int vi = t + i * 256;
        int ch = vi / 48;
        int off = (vi % 48) * 8;
        int g = (r0 - 1) * 64 + off;
        int4 val = {0, 0, 0, 0};
        if ((unsigned)g < 4096u)
            val = *(const int4*)(v_cn + (((long)(b * CCH + c0 + ch)) << 12) + g);
        *(int4*)&in_t[ch * 384 + off] = val;
    }
    __syncthreads();

    const int lane = t & 63, w = t >> 6;
#pragma unroll
    for (int i = 0; i < 8; ++i) {
        int ch = w * 8 + i;
        float cr[6], lf[6], rf[6];
#pragma unroll
        for (int rr = 0; rr < 6; ++rr) {
            cr[rr] = (float)in_t[ch * 384 + rr * 64 + lane];
            float lv = __shfl_up(cr[rr], 1);
            float rv = __shfl_down(cr[rr], 1);
            lf[rr] = (lane == 0) ? 0.f : lv;
            rf[rr] = (lane == 63) ? 0.f : rv;
        }
        float w0 = wls[ch*9+0], w1 = wls[ch*9+1], w2 = wls[ch*9+2];
        float w3 = wls[ch*9+3], w4 = wls[ch*9+4], w5 = wls[ch*9+5];
        float w6 = wls[ch*9+6], w7 = wls[ch*9+7], w8 = wls[ch*9+8];
        float bias = bls[ch];
#pragma unroll
        for (int r = 0; r < 4; ++r) {
            float acc = bias
                + lf[r]   * w0 + cr[r]   * w1 + rf[r]   * w2
                + lf[r+1] * w3 + cr[r+1] * w4 + rf[r+1] * w5
                + lf[r+2] * w6 + cr[r+2] * w7 + rf[r+2] * w8;
            tile_bf[(r * 64 + lane) * 33 + ch] = __float2bfloat16(acc);
        }
    }
    __syncthreads();
#pragma unroll
    for (int i = 0; i < 32; ++i) {
        int idx = t + i * 256;
        int nl = idx >> 5, cj = idx & 31;
        int sp = n0 + nl;
        lepe_cn[((long)(b * CCH + (sp >> 4)) << 12) + (nl & 15) * 256 + c0 + cj] =
            tile_bf[nl * 33 + cj];
    }
}

// mega2: stage1 [0,512) | lepe [512,1024)
__global__ __launch_bounds__(256)
void mega2_kernel(const __hip_bfloat16* __restrict__ qk_nc,
                  const __hip_bfloat16* __restrict__ v_cn,
                  const __hip_bfloat16* __restrict__ st_md,
                  __hip_bfloat16* __restrict__ opart,
                  const float* __restrict__ lw, const float* __restrict__ lb,
                  __hip_bfloat16* __restrict__ lepe_cn)
{
    __shared__ __align__(16) char smem[57344];
    int blk = blockIdx.x;
    if (blk < 512) {
        stage1_dev(smem, blk & 15, blk >> 4, qk_nc, v_cn, st_md, opart);
    } else {
        int j = blk - 512;
        lepe_dev(smem, j & 15, (j >> 4) & 7, j >> 7, v_cn, lw, lb, lepe_cn);
    }
}

// Merge stage-1 partials -> sout_bf[bh][d][m]  (coalesced bf16 reads)
__global__ __launch_bounds__(256)
void merge1_kernel(const __hip_bfloat16* __restrict__ opart, __hip_bfloat16* __restrict__ sout)
{
    int t = blockIdx.x * 256 + threadIdx.x;   // 262144
    int m = t & 255;
    int d = (t >> 8) & 31;
    int bh = t >> 13;
    float num = 0.f, den = 0.f;
    for (int ch = 0; ch < 16; ++ch) {
        long base = (long)((ch * 32 + bh) * 33) * 256 + m;
        num += (float)opart[base + (long)d * 256];
        den += (float)opart[base + 32 * 256];
    }
    sout[(long)bh * 8192 + d * 256 + m] = __float2bfloat16(num / den);
}

// ---------------------------------------------------------------------------
// Stage-2 MFMA attention + lepe add.  Writes final out[b][c][n].
// stfrag read direct from global (st_md L2-hot); qf pipelined one sub ahead.
__global__ __launch_bounds__(256)
void stage2_mfma(const __hip_bfloat16* __restrict__ qk_nc,
                 const __hip_bfloat16* __restrict__ st_md,
                 const __hip_bfloat16* __restrict__ sout_bf,
                 const __hip_bfloat16* __restrict__ lepe_cn,
                 float* __restrict__ out)
{
    __shared__ __hip_bfloat16 Es2[64 * 264];
    __shared__ __hip_bfloat16 sos[32 * 264];
    __shared__ float o_t[32 * 68];
    const int chunk = blockIdx.x, bh = blockIdx.y;
    const int b = bh >> 3, h = bh & 7;
    const int t = threadIdx.x, lane = t & 63, w = t >> 6;
    const int l15 = lane & 15, quad = lane >> 4;
    const int n0 = chunk * 256;

    {
        int row = t >> 3, seg = t & 7;
        const int4* src = (const int4*)(sout_bf + (long)bh * 8192 + row * 256 + seg * 32);
        int4* dst = (int4*)&sos[row * 264 + seg * 32];
        dst[0] = src[0]; dst[1] = src[1]; dst[2] = src[2]; dst[3] = src[3];
    }
    bf16x8 stfrag[4];
#pragma unroll
    for (int mt = 0; mt < 4; ++mt)
        stfrag[mt] = *(const bf16x8*)(st_md
            + ((long)(b * 256 + 64 * w + mt * 16 + l15)) * 256 + h * 32 + quad * 8);
    const __hip_bfloat16* qfp = qk_nc + ((long)b * 4096 + n0 + l15) * 512 + h * 32 + quad * 8;
    bf16x8 qq[4][4];
#pragma unroll
    for (int nt = 0; nt < 4; ++nt)
        qq[0][nt] = *(const bf16x8*)(qfp + (long)(nt * 16) * 512);
    bf16x8 onesf;
    { short o = (l15 == 0) ? (short)0x3F80 : (short)0;
      onesf = bf16x8{o, o, o, o, o, o, o, o}; }
    __syncthreads();

#pragma unroll
    for (int sub = 0; sub < 4; ++sub) {
        const int nbase = n0 + sub * 64;
#pragma unroll
        for (int nt = 0; nt < 4; ++nt) {
            bf16x8 qf = qq[sub][nt];
#pragma unroll
            for (int mt = 0; mt < 4; ++mt) {
                f32x4 s = __builtin_amdgcn_mfma_f32_16x16x32_bf16(qf, stfrag[mt], f32x4{0.f,0.f,0.f,0.f}, 0, 0, 0);
#pragma unroll
                for (int r = 0; r < 4; ++r)
                    Es2[(nt * 16 + quad * 4 + r) * 264 + 64 * w + mt * 16 + l15] =
                        __float2bfloat16(__expf(s[r] * SCALE));
            }
        }
        if (sub < 3) {                        // prefetch sub+1 (crosses barrier)
#pragma unroll
            for (int nt = 0; nt < 4; ++nt)
                qq[sub + 1][nt] = *(const bf16x8*)(qfp + (long)((sub + 1) * 64 + nt * 16) * 512);
        }
        __syncthreads();
        f32x4 o0 = {0.f,0.f,0.f,0.f}, o1 = o0, o2 = o0;
#pragma unroll
        for (int ks = 0; ks < 8; ++ks) {
            bf16x8 af = *(const bf16x8*)&Es2[(16 * w + l15) * 264 + ks * 32 + quad * 8];
            bf16x8 b0 = *(const bf16x8*)&sos[(l15) * 264 + ks * 32 + quad * 8];
            bf16x8 b1 = *(const bf16x8*)&sos[(16 + l15) * 264 + ks * 32 + quad * 8];
            o0 = __builtin_amdgcn_mfma_f32_16x16x32_bf16(af, b0, o0, 0, 0, 0);
            o1 = __builtin_amdgcn_mfma_f32_16x16x32_bf16(af, b1, o1, 0, 0, 0);
            o2 = __builtin_amdgcn_mfma_f32_16x16x32_bf16(af, onesf, o2, 0, 0, 0);
        }
        __syncthreads();
#pragma unroll
        for (int r = 0; r < 4; ++r) {
            float den = __shfl(o2[r], lane & 48);
            float inv = 1.f / den;
            o_t[(l15) * 68 + 16 * w + quad * 4 + r]      = o0[r] * inv;
            o_t[(16 + l15) * 68 + 16 * w + quad * 4 + r] = o1[r] * inv;
        }
        __syncthreads();
        {
            int row = t >> 3, coff = (t & 7) * 8;
            long gb = ((long)(b * 256 + h * 32 + row)) * 4096 + nbase + coff;
            int4 lp4 = *(const int4*)(lepe_cn + gb);
            const __hip_bfloat16* lp = (const __hip_bfloat16*)&lp4;
            const float* sp = &o_t[row * 68 + coff];
            float4 r0, r1;
            r0.x = sp[0] + (float)lp[0]; r0.y = sp[1] + (float)lp[1];
            r0.z = sp[2] + (float)lp[2]; r0.w = sp[3] + (float)lp[3];
            r1.x = sp[4] + (float)lp[4]; r1.y = sp[5] + (float)lp[5];
            r1.z = sp[6] + (float)lp[6]; r1.w = sp[7] + (float)lp[7];
            *(float4*)(out + gb)     = r0;
            *(float4*)(out + gb + 4) = r1;
        }
        __syncthreads();
    }
}

// ---------------------------------------------------------------------------
extern "C" void kernel_launch(void* const* d_in, const int* in_sizes, int n_in,
                              void* d_out, int out_size, void* d_ws, size_t ws_size,
                              hipStream_t stream)
{
    const float* x    = (const float*)d_in[0];
    const float* aff  = (const float*)d_in[1];
    const float* nw   = (const float*)d_in[2];
    const float* nb   = (const float*)d_in[3];
    const float* Wq   = (const float*)d_in[4];
    const float* Wk   = (const float*)d_in[5];
    const float* Wv   = (const float*)d_in[6];
    const float* Wsp  = (const float*)d_in[7];
    const float* lw   = (const float*)d_in[8];
    const float* lb   = (const float*)d_in[9];
    float* out = (float*)d_out;

    float* ws = (float*)d_ws;
    const long P = PLANE;
    __hip_bfloat16* qk_nc  = (__hip_bfloat16*)(ws);           // [b][n][512] bf16 (16.8MB)
    __hip_bfloat16* v_cn   = (__hip_bfloat16*)(ws + 4 * P);   // [b][c][n]
    __hip_bfloat16* xn_cn  = (__hip_bfloat16*)(ws + 6 * P);
    __hip_bfloat16* xn_nc  = (__hip_bfloat16*)(ws + 8 * P);
    __hip_bfloat16* lepe_cn= (__hip_bfloat16*)(ws + 10 * P);
    float* stoken_part = ws + 14 * P;                          // 32 x 65536 f32
    __hip_bfloat16* opart = (__hip_bfloat16*)(ws + 16 * P);    // 16*32*33*256 bf16
    float* tail        = ws + 16 * P + 2162688;
    __hip_bfloat16* wbf       = (__hip_bfloat16*)tail;
    __hip_bfloat16* st_md     = (__hip_bfloat16*)(tail + 262144);
    __hip_bfloat16* sout_bf   = (__hip_bfloat16*)(tail + 393216);
    float* rs_part = tail + 525312;

    // 1. fused LayerNorm (register-resident) + weight casts
    ln_fused_kernel<<<260, 512, 0, stream>>>(x, nw, nb, Wq, Wk, Wv, Wsp,
                                             xn_cn, xn_nc, wbf);
    // 2. mega1: stoken (staged K-loop) + q/k + v (128x128 one-shot, XCD-colocated)
    mega1_kernel<<<896, 256, 0, stream>>>(aff, xn_cn, xn_nc, wbf,
                                          qk_nc, v_cn, stoken_part, rs_part);
    // 3. st_md with fused split-K(8) + rowsum reduce + rowscale
    stmd_kernel<<<64, 256, 0, stream>>>(stoken_part, wbf + 3 * 65536, st_md, rs_part);
    // 4. mega2: stage-1 attention partials (v/kf pipelined) + lepe conv
    mega2_kernel<<<1024, 256, 0, stream>>>(qk_nc, v_cn, st_md, opart, lw, lb, lepe_cn);
    // 5. merge -> sout_bf
    merge1_kernel<<<1024, 256, 0, stream>>>(opart, sout_bf);
    // 6. stage-2 attention (qf pipelined) + lepe add -> d_out
    stage2_mfma<<<dim3(16, 32), 256, 0, stream>>>(qk_nc, st_md, sout_bf, lepe_cn, out);
}

// Round 7
// 189.351 us; speedup vs baseline: 1.1419x; 1.0341x over previous
//
#include <hip/hip_runtime.h>
#include <hip/hip_bf16.h>

#define BATCH 4
#define CCH   256
#define HWHW  4096
#define NSP   256
#define NHEAD 8
#define SCALE 0.17677669529663689f
#define PLANE 1048576L

typedef short bf16x8 __attribute__((ext_vector_type(8)));
typedef short bf16x4 __attribute__((ext_vector_type(4)));
typedef float f32x4  __attribute__((ext_vector_type(4)));

__device__ __forceinline__ short f2bs(float f) {
    __hip_bfloat16 h = __float2bfloat16(f);
    return *(short*)&h;
}
__device__ __forceinline__ bf16x8 cvt8(float4 a, float4 b) {
    bf16x8 p;
    p[0] = f2bs(a.x); p[1] = f2bs(a.y); p[2] = f2bs(a.z); p[3] = f2bs(a.w);
    p[4] = f2bs(b.x); p[5] = f2bs(b.y); p[6] = f2bs(b.z); p[7] = f2bs(b.w);
    return p;
}
// async global->LDS, 16B per lane; LDS dest = base + lane*16 (wave-uniform base)
__device__ __forceinline__ void gll16(const __hip_bfloat16* g, __hip_bfloat16* l) {
    __builtin_amdgcn_global_load_lds(
        (const __attribute__((address_space(1))) unsigned int*)(const void*)g,
        (__attribute__((address_space(3))) unsigned int*)(void*)l,
        16, 0, 0);
}

// ---------------------------------------------------------------------------
// Fused LayerNorm -> xn_cn [b][c][n] + xn_nc [b][n][c] (bf16), register-
// resident: 512 thr/block, thread owns 8 channels x 4 pixels. Blocks 256..259: W casts.
__global__ __launch_bounds__(512)
void ln_fused_kernel(const float* __restrict__ x, const float* __restrict__ w,
                     const float* __restrict__ bb,
                     const float* __restrict__ Wq, const float* __restrict__ Wk,
                     const float* __restrict__ Wv, const float* __restrict__ Wsp,
                     __hip_bfloat16* __restrict__ xn_cn,
                     __hip_bfloat16* __restrict__ xn_nc,
                     __hip_bfloat16* __restrict__ wbf)
{
    __shared__ float ps[32][64], pss[32][64];
    __shared__ float mus[64], rstds[64];
    __shared__ float wls[256], bls[256];
    int blk = blockIdx.x;
    int t = threadIdx.x;
    if (blk >= 256) {                        // weight casts
        int sel = blk - 256;
        const float* src = (sel == 0) ? Wq : (sel == 1) ? Wk : (sel == 2) ? Wv : Wsp;
        __hip_bfloat16* dst = wbf + sel * 65536;
        for (int i = t * 4; i < 65536; i += 2048) {
            float4 f = *(const float4*)(src + i);
            __hip_bfloat16 p[4];
            p[0] = __float2bfloat16(f.x); p[1] = __float2bfloat16(f.y);
            p[2] = __float2bfloat16(f.z); p[3] = __float2bfloat16(f.w);
            *(int2*)(dst + i) = *(int2*)p;
        }
        return;
    }
    int b = blk >> 6;
    int n0 = (blk & 63) * 64;
    int pg = t & 15;                         // pixel group: 4 pixels
    int cq = t >> 4;                         // channel group: 8 channels
    if (t < 256) { wls[t] = w[t]; bls[t] = bb[t]; }

    const float* xp = x + ((long)(b * CCH + cq * 8)) * HWHW + n0 + pg * 4;
    float4 v[8];
#pragma unroll
    for (int i = 0; i < 8; ++i) v[i] = *(const float4*)(xp + (long)i * HWHW);
    float4 s = {0.f,0.f,0.f,0.f}, ss = {0.f,0.f,0.f,0.f};
#pragma unroll
    for (int i = 0; i < 8; ++i) {
        s.x += v[i].x; s.y += v[i].y; s.z += v[i].z; s.w += v[i].w;
        ss.x += v[i].x * v[i].x; ss.y += v[i].y * v[i].y;
        ss.z += v[i].z * v[i].z; ss.w += v[i].w * v[i].w;
    }
    *(float4*)&ps[cq][pg * 4]  = s;
    *(float4*)&pss[cq][pg * 4] = ss;
    __syncthreads();
    if (t < 64) {
        float S = 0.f, SS = 0.f;
#pragma unroll
        for (int q = 0; q < 32; ++q) { S += ps[q][t]; SS += pss[q][t]; }
        float mu = S * (1.f / 256.f);
        float var = SS * (1.f / 256.f) - mu * mu;
        mus[t] = mu; rstds[t] = rsqrtf(var + 1e-6f);
    }
    __syncthreads();
    float4 mu4 = *(float4*)&mus[pg * 4];
    float4 rs4 = *(float4*)&rstds[pg * 4];

    bf16x8 pk[4];                            // [pixel j][channel i]
#pragma unroll
    for (int i = 0; i < 8; ++i) {
        int c = cq * 8 + i;
        float wc = wls[c], bc = bls[c];
        short h0 = f2bs((v[i].x - mu4.x) * rs4.x * wc + bc);
        short h1 = f2bs((v[i].y - mu4.y) * rs4.y * wc + bc);
        short h2 = f2bs((v[i].z - mu4.z) * rs4.z * wc + bc);
        short h3 = f2bs((v[i].w - mu4.w) * rs4.w * wc + bc);
        pk[0][i] = h0; pk[1][i] = h1; pk[2][i] = h2; pk[3][i] = h3;
        bf16x4 q; q[0] = h0; q[1] = h1; q[2] = h2; q[3] = h3;
        *(bf16x4*)(xn_cn + ((long)(b * CCH + c)) * HWHW + n0 + pg * 4) = q;
    }
#pragma unroll
    for (int j = 0; j < 4; ++j)
        *(bf16x8*)(xn_nc + ((long)b * HWHW + n0 + pg * 4 + j) * CCH + cq * 8) = pk[j];
}

// ---------------------------------------------------------------------------
// K=256 one-shot 128x128 GEMM: stage full A-tile (128x256 bf16 = 64KB) into
// LDS once via 64 gll16 in slab layout [rowtile][kslot], ONE barrier, then
// each wave computes a 64x64 quadrant: 4x4 accs = 128 MFMAs, B fragments
// direct-from-global with one-deep register prefetch.  Bit-identical k order.
__device__ __forceinline__ void gemm_k256_128(
    const __hip_bfloat16* __restrict__ A, const __hip_bfloat16* __restrict__ B,
    __hip_bfloat16* __restrict__ C, int bx, int by, int bz,
    int N, long aStrideZ, long bStrideZ, long cStrideZ,
    __hip_bfloat16* __restrict__ Asm)
{
    const int K = 256;
    const int t = threadIdx.x, lane = t & 63, w = t >> 6;
    const int l15 = lane & 15, quad = lane >> 4;
    const int Mt = by * 128, Nt = bx * 128;
    {
        const __hip_bfloat16* aBase = A + (long)bz * aStrideZ
            + (long)(Mt + l15) * K + quad * 8;
#pragma unroll
        for (int p = 0; p < 16; ++p) {
            const int rt = w * 2 + (p >> 3), s = p & 7;
            gll16(aBase + (long)(rt * 16) * K + s * 32, Asm + (rt * 8 + s) * 512);
        }
    }
    const int wm2 = w & 1, wn2 = w >> 1;
    const __hip_bfloat16* bBase = B + (long)bz * bStrideZ
        + (long)(Nt + wn2 * 64 + l15) * K + quad * 8;

    f32x4 acc[4][4];
#pragma unroll
    for (int mi = 0; mi < 4; ++mi)
#pragma unroll
        for (int nj = 0; nj < 4; ++nj) acc[mi][nj] = f32x4{0.f,0.f,0.f,0.f};

    bf16x8 bEv[4], bOd[4];
#pragma unroll
    for (int nj = 0; nj < 4; ++nj)
        bEv[nj] = *(const bf16x8*)(bBase + (long)(nj * 16) * K);
    __syncthreads();                          // A tile ready
#pragma unroll
    for (int sp = 0; sp < 4; ++sp) {
        const int s0 = 2 * sp, s1 = 2 * sp + 1;
#pragma unroll
        for (int nj = 0; nj < 4; ++nj)       // prefetch odd slot
            bOd[nj] = *(const bf16x8*)(bBase + (long)(nj * 16) * K + s1 * 32);
#pragma unroll
        for (int mi = 0; mi < 4; ++mi) {
            bf16x8 a = *(const bf16x8*)&Asm[((wm2 * 4 + mi) * 8 + s0) * 512 + lane * 8];
            acc[mi][0] = __builtin_amdgcn_mfma_f32_16x16x32_bf16(a, bEv[0], acc[mi][0], 0, 0, 0);
            acc[mi][1] = __builtin_amdgcn_mfma_f32_16x16x32_bf16(a, bEv[1], acc[mi][1], 0, 0, 0);
            acc[mi][2] = __builtin_amdgcn_mfma_f32_16x16x32_bf16(a, bEv[2], acc[mi][2], 0, 0, 0);
            acc[mi][3] = __builtin_amdgcn_mfma_f32_16x16x32_bf16(a, bEv[3], acc[mi][3], 0, 0, 0);
        }
        if (sp < 3) {
#pragma unroll
            for (int nj = 0; nj < 4; ++nj)   // prefetch next even slot
                bEv[nj] = *(const bf16x8*)(bBase + (long)(nj * 16) * K + (s0 + 2) * 32);
        }
#pragma unroll
        for (int mi = 0; mi < 4; ++mi) {
            bf16x8 a = *(const bf16x8*)&Asm[((wm2 * 4 + mi) * 8 + s1) * 512 + lane * 8];
            acc[mi][0] = __builtin_amdgcn_mfma_f32_16x16x32_bf16(a, bOd[0], acc[mi][0], 0, 0, 0);
            acc[mi][1] = __builtin_amdgcn_mfma_f32_16x16x32_bf16(a, bOd[1], acc[mi][1], 0, 0, 0);
            acc[mi][2] = __builtin_amdgcn_mfma_f32_16x16x32_bf16(a, bOd[2], acc[mi][2], 0, 0, 0);
            acc[mi][3] = __builtin_amdgcn_mfma_f32_16x16x32_bf16(a, bOd[3], acc[mi][3], 0, 0, 0);
        }
    }
#pragma unroll
    for (int mi = 0; mi < 4; ++mi)
#pragma unroll
        for (int nj = 0; nj < 4; ++nj)
#pragma unroll
            for (int r = 0; r < 4; ++r) {
                int m = Mt + wm2 * 64 + mi * 16 + quad * 4 + r;
                int n = Nt + wn2 * 64 + nj * 16 + l15;
                C[(long)bz * cStrideZ + (long)m * N + n] =
                    __float2bfloat16(acc[mi][nj][r]);
            }
}

// ---------------------------------------------------------------------------
// bf16 MFMA NT GEMM body, BK=64 (for large-K / fp32-A cases).
// ASTAGE: 1 = A fp32 reg-convert (prefetched);
//         2 = A = sum of 8 fp32 planes (stride 65536) + fused rowscale (rsl).
// ROWSUM: emit rsPart[z*256+m].  NTL: N-tiles per block.
template <int OUTK, int ASTAGE, bool ROWSUM, int NTL>
__device__ __forceinline__ void gemm_body(
    const void* __restrict__ Av, const __hip_bfloat16* __restrict__ B,
    void* __restrict__ Cptr, int bx, int by, int bz,
    int N, int K, int kChunk, int kShift,
    long aStrideZ, long bStrideZ, long cStrideZ,
    float* __restrict__ rsPart,
    __hip_bfloat16* __restrict__ Asm, __hip_bfloat16* __restrict__ Bsm,
    float* __restrict__ rsl)
{
    int z = bz;
    int b = z >> kShift;
    int ch = z & ((1 << kShift) - 1);
    int t = threadIdx.x;
    int lane = t & 63, w = t >> 6;
    int l15 = lane & 15, quad = lane >> 4;
    int Mt = by * 64, Nt = bx * 64 * NTL;

    if (ASTAGE == 2 && t < 64) {             // fused rowsum reduce (8 chunks)
        float s = 0.f;
#pragma unroll
        for (int pl = 0; pl < 8; ++pl) s += rsPart[((b * 8 + pl) << 8) + Mt + t];
        rsl[t] = s;
    }

    long aOff = (long)b * aStrideZ + (long)ch * kChunk
        + (long)(Mt + w * 16 + l15) * K + quad * 8;
    const float* aSrcF = (const float*)Av + aOff;
    const __hip_bfloat16* bSrc = B + (long)b * bStrideZ + (long)ch * kChunk
        + (long)(Nt + w * 16 + l15) * K + quad * 8;

    f32x4 acc[NTL][2][2];
#pragma unroll
    for (int nt = 0; nt < NTL; ++nt)
#pragma unroll
        for (int i = 0; i < 2; ++i)
#pragma unroll
            for (int j = 0; j < 2; ++j) acc[nt][i][j] = f32x4{0.f,0.f,0.f,0.f};
    f32x4 rs0 = {0.f,0.f,0.f,0.f}, rs1 = rs0;
    bf16x8 onesf;
    { short o = (l15 == 0) ? (short)0x3F80 : (short)0;
      onesf = bf16x8{o, o, o, o, o, o, o, o}; }
    int wm = (w & 1) * 2, wn = (w >> 1) * 2;

    float4 pf0, pf1, pf2, pf3;
    if (ASTAGE == 1) {
        pf0 = *(const float4*)(aSrcF);      pf1 = *(const float4*)(aSrcF + 4);
        pf2 = *(const float4*)(aSrcF + 32); pf3 = *(const float4*)(aSrcF + 36);
    }

    const bf16x8* AsmU = (const bf16x8*)Asm;
    const bf16x8* BsmU = (const bf16x8*)Bsm;

    for (int k0 = 0; k0 < kChunk; k0 += 64) {
        // ---- stage A ----
        if (ASTAGE == 1) {
            *(bf16x8*)&Asm[t * 8]        = cvt8(pf0, pf1);
            *(bf16x8*)&Asm[2048 + t * 8] = cvt8(pf2, pf3);
        } else {                              // 8-plane fp32 sum
#pragma unroll
            for (int kh = 0; kh < 2; ++kh) {
                float4 s0 = {0.f,0.f,0.f,0.f}, s1 = {0.f,0.f,0.f,0.f};
#pragma unroll
                for (int pl = 0; pl < 8; ++pl) {
                    const float* p = aSrcF + (long)pl * 65536 + k0 + kh * 32;
                    float4 u0 = *(const float4*)p, u1 = *(const float4*)(p + 4);
                    s0.x += u0.x; s0.y += u0.y; s0.z += u0.z; s0.w += u0.w;
                    s1.x += u1.x; s1.y += u1.y; s1.z += u1.z; s1.w += u1.w;
                }
                *(bf16x8*)&Asm[kh * 2048 + t * 8] = cvt8(s0, s1);
            }
        }
        // ---- stage B (bf16, async direct-to-LDS) ----
#pragma unroll
        for (int nt = 0; nt < NTL; ++nt) {
            gll16(bSrc + (long)nt * 64 * K + k0,      Bsm + nt * 4096 + w * 512);
            gll16(bSrc + (long)nt * 64 * K + k0 + 32, Bsm + nt * 4096 + 2048 + w * 512);
        }
        __syncthreads();
        if (ASTAGE == 1 && k0 + 64 < kChunk) {   // prefetch next A chunk
            const float* nx = aSrcF + k0 + 64;
            pf0 = *(const float4*)nx;        pf1 = *(const float4*)(nx + 4);
            pf2 = *(const float4*)(nx + 32); pf3 = *(const float4*)(nx + 36);
        }
        // ---- MFMA ----
#pragma unroll
        for (int kh = 0; kh < 2; ++kh) {
            bf16x8 a0 = AsmU[kh * 256 + wm * 64 + lane];
            bf16x8 a1 = AsmU[kh * 256 + (wm + 1) * 64 + lane];
            if (ROWSUM) {
                rs0 = __builtin_amdgcn_mfma_f32_16x16x32_bf16(a0, onesf, rs0, 0, 0, 0);
                rs1 = __builtin_amdgcn_mfma_f32_16x16x32_bf16(a1, onesf, rs1, 0, 0, 0);
            }
#pragma unroll
            for (int nt = 0; nt < NTL; ++nt) {
                bf16x8 b0 = BsmU[nt * 512 + kh * 256 + wn * 64 + lane];
                bf16x8 b1 = BsmU[nt * 512 + kh * 256 + (wn + 1) * 64 + lane];
                acc[nt][0][0] = __builtin_amdgcn_mfma_f32_16x16x32_bf16(a0, b0, acc[nt][0][0], 0, 0, 0);
                acc[nt][0][1] = __builtin_amdgcn_mfma_f32_16x16x32_bf16(a0, b1, acc[nt][0][1], 0, 0, 0);
                acc[nt][1][0] = __builtin_amdgcn_mfma_f32_16x16x32_bf16(a1, b0, acc[nt][1][0], 0, 0, 0);
                acc[nt][1][1] = __builtin_amdgcn_mfma_f32_16x16x32_bf16(a1, b1, acc[nt][1][1], 0, 0, 0);
            }
        }
        __syncthreads();
    }
    if (ROWSUM && bx == 0 && (w >> 1) == 0 && l15 == 0) {
#pragma unroll
        for (int r = 0; r < 4; ++r) {
            rsPart[(long)z * 256 + Mt + wm * 16 + quad * 4 + r]       = rs0[r];
            rsPart[(long)z * 256 + Mt + (wm + 1) * 16 + quad * 4 + r] = rs1[r];
        }
    }
#pragma unroll
    for (int nt = 0; nt < NTL; ++nt)
#pragma unroll
        for (int i = 0; i < 2; ++i)
#pragma unroll
            for (int j = 0; j < 2; ++j)
#pragma unroll
                for (int r = 0; r < 4; ++r) {
                    int m = Mt + (wm + i) * 16 + quad * 4 + r;
                    int n = Nt + nt * 64 + (wn + j) * 16 + l15;
                    float val = acc[nt][i][j][r];
                    if (ASTAGE == 2) val /= (rsl[m - Mt] + 1e-16f);
                    long off = (long)z * cStrideZ + (long)m * N + n;
                    if (OUTK == 0) ((float*)Cptr)[off] = val;
                    else ((__hip_bfloat16*)Cptr)[off] = __float2bfloat16(val);
                }
}

// mega1: stoken [0,128) | q+k 128-tile [128,640) | v 128-tile [640,896)
__global__ __launch_bounds__(256, 2)
void mega1_kernel(const float* __restrict__ aff,
                  const __hip_bfloat16* __restrict__ xn_cn,
                  const __hip_bfloat16* __restrict__ xn_nc,
                  const __hip_bfloat16* __restrict__ wbf,
                  __hip_bfloat16* __restrict__ qk_nc,
                  __hip_bfloat16* __restrict__ v_cn,
                  float* __restrict__ stoken_part,
                  float* __restrict__ rs_part)
{
    __shared__ __align__(16) char smem[65536];
    __hip_bfloat16* Asm = (__hip_bfloat16*)smem;            // stoken: 8KB
    __hip_bfloat16* Bsm = (__hip_bfloat16*)(smem + 8192);   // stoken: 32KB
    __hip_bfloat16* A128 = (__hip_bfloat16*)smem;           // 128-tile: 64KB
    int blk = blockIdx.x;
    if (blk < 128) {          // stoken partials; same-z (shared B) 32 apart
        int i = blk;
        gemm_body<0, 1, true, 4>(aff, xn_cn, stoken_part,
            0, i >> 5, i & 31, 256, 4096, 512, 3,
            PLANE, PLANE, 65536L, rs_part, Asm, Bsm, nullptr);
    } else if (blk < 640) {   // fused q+k: A=xn_nc tile shared by bx=0..3
        int i = blk - 128;
        int bx = i >> 7, rem = i & 127;
        gemm_k256_128(xn_nc, wbf, qk_nc,
            bx, rem >> 2, rem & 3, 512, PLANE, 0L, 2 * PLANE, A128);
    } else {                  // v_cn: B=xn_nc tile shared by by=0..1
        int i = blk - 640;
        int by = i >> 7, rem = i & 127;
        gemm_k256_128(wbf + 2 * 65536, xn_nc, v_cn,
            rem >> 2, by, rem & 3, 4096, 0L, PLANE, PLANE, A128);
    }
}

// ---------------------------------------------------------------------------
// Depthwise 3x3 conv + scramble-transpose (device fn; smem carved by caller).
__device__ __forceinline__
void lepe_dev(char* smem, int bx, int cy, int b,
              const __hip_bfloat16* __restrict__ v_cn,
              const float* __restrict__ lw, const float* __restrict__ lb,
              __hip_bfloat16* __restrict__ lepe_cn)
{
    __hip_bfloat16* in_t    = (__hip_bfloat16*)smem;            // 32*384*2 = 24576
    __hip_bfloat16* tile_bf = (__hip_bfloat16*)(smem + 24576);  // 256*33*2 = 16896
    float* wls = (float*)(smem + 41472);                        // 288*4
    float* bls = (float*)(smem + 42624);                        // 32*4
    const int c0 = cy * 32;
    const int t = threadIdx.x;
    const int n0 = bx * 256, r0 = bx * 4;

    for (int i = t; i < 288; i += 256) wls[i] = lw[c0 * 9 + i];
    if (t < 32)  bls[t] = lb[c0 + t];
#pragma unroll
    for (int i = 0; i < 6; ++i) {
        int vi = t + i * 256;
        int ch = vi / 48;
        int off = (vi % 48) * 8;
        int g = (r0 - 1) * 64 + off;
        int4 val = {0, 0, 0, 0};
        if ((unsigned)g < 4096u)
            val = *(const int4*)(v_cn + (((long)(b * CCH + c0 + ch)) << 12) + g);
        *(int4*)&in_t[ch * 384 + off] = val;
    }
    __syncthreads();

    const int lane = t & 63, w = t >> 6;
#pragma unroll
    for (int i = 0; i < 8; ++i) {
        int ch = w * 8 + i;
        float cr[6], lf[6], rf[6];
#pragma unroll
        for (int rr = 0; rr < 6; ++rr) {
            cr[rr] = (float)in_t[ch * 384 + rr * 64 + lane];
            float lv = __shfl_up(cr[rr], 1);
            float rv = __shfl_down(cr[rr], 1);
            lf[rr] = (lane == 0) ? 0.f : lv;
            rf[rr] = (lane == 63) ? 0.f : rv;
        }
        float w0 = wls[ch*9+0], w1 = wls[ch*9+1], w2 = wls[ch*9+2];
        float w3 = wls[ch*9+3], w4 = wls[ch*9+4], w5 = wls[ch*9+5];
        float w6 = wls[ch*9+6], w7 = wls[ch*9+7], w8 = wls[ch*9+8];
        float bias = bls[ch];
#pragma unroll
        for (int r = 0; r < 4; ++r) {
            float acc = bias
                + lf[r]   * w0 + cr[r]   * w1 + rf[r]   * w2
                + lf[r+1] * w3 + cr[r+1] * w4 + rf[r+1] * w5
                + lf[r+2] * w6 + cr[r+2] * w7 + rf[r+2] * w8;
            tile_bf[(r * 64 + lane) * 33 + ch] = __float2bfloat16(acc);
        }
    }
    __syncthreads();
#pragma unroll
    for (int i = 0; i < 32; ++i) {
        int idx = t + i * 256;
        int nl = idx >> 5, cj = idx & 31;
        int sp = n0 + nl;
        lepe_cn[((long)(b * CCH + (sp >> 4)) << 12) + (nl & 15) * 256 + c0 + cj] =
            tile_bf[nl * 33 + cj];
    }
}

// stmd_lepe: stmd [0,64) | lepe [64,576) — both depend only on mega1 outputs.
// Fills the CUs that the 64-block stmd previously left idle.
__global__ __launch_bounds__(256)
void stmd_lepe_kernel(const float* __restrict__ part,
                      const __hip_bfloat16* __restrict__ wsp,
                      __hip_bfloat16* __restrict__ st_md,
                      float* __restrict__ rs_part,
                      const __hip_bfloat16* __restrict__ v_cn,
                      const float* __restrict__ lw, const float* __restrict__ lb,
                      __hip_bfloat16* __restrict__ lepe_cn)
{
    __shared__ __align__(16) char smem[43008];
    int blk = blockIdx.x;
    if (blk < 64) {
        __hip_bfloat16* Asm = (__hip_bfloat16*)smem;
        __hip_bfloat16* Bsm = (__hip_bfloat16*)(smem + 8192);
        float* rsl = (float*)(smem + 16384);
        int i = blk;
        gemm_body<1, 2, false, 1>(part, wsp, st_md,
            i & 3, (i >> 2) & 3, i >> 4, 256, 256, 256, 0,
            524288L, 0L, 65536L, rs_part, Asm, Bsm, rsl);
    } else {
        int j = blk - 64;
        lepe_dev(smem, j & 15, (j >> 4) & 7, j >> 7, v_cn, lw, lb, lepe_cn);
    }
}

// ---------------------------------------------------------------------------
// Stage-1 MFMA attention partials.  sts aliases Es (dead after afrag load,
// fenced by one extra barrier) -> 36.9KB LDS, up to 4 blocks/CU.
// v/kf operands software-pipelined one sub ahead into registers.
__global__ __launch_bounds__(256)
void mega2_kernel(const __hip_bfloat16* __restrict__ qk_nc,
                  const __hip_bfloat16* __restrict__ v_cn,
                  const __hip_bfloat16* __restrict__ st_md,
                  __hip_bfloat16* __restrict__ opart)
{
    __shared__ __align__(16) char smem[36864];
    __hip_bfloat16* Es  = (__hip_bfloat16*)smem;            // 256*72*2 = 36864
    __hip_bfloat16* sts = (__hip_bfloat16*)smem;            // alias: dead before Es use
    const int chunk = blockIdx.x & 15, bh = blockIdx.x >> 4;
    const int b = bh >> 3, h = bh & 7;
    const int t = threadIdx.x, lane = t & 63, w = t >> 6;
    const int l15 = lane & 15, quad = lane >> 4;
    const int n0 = chunk * 256;

    {
        const int4* src = (const int4*)(st_md + ((long)(b * 256 + t)) * 256 + h * 32);
        int4* dst = (int4*)&sts[t * 40];
        dst[0] = src[0]; dst[1] = src[1]; dst[2] = src[2]; dst[3] = src[3];
    }
    // prefetch sub-0 operands while sts staging is in flight
    const __hip_bfloat16* kfp = qk_nc + ((long)b * 4096 + n0 + 16 * w + l15) * 512 + 256 + h * 32 + quad * 8;
    const __hip_bfloat16* vp0 = v_cn + ((long)(b * 256 + h * 32 + l15)) * 4096 + n0 + quad * 8;
    const __hip_bfloat16* vp1 = vp0 + 16 * 4096;
    bf16x8 kfs[4], vv[4][4];
    kfs[0]   = *(const bf16x8*)(kfp);
    vv[0][0] = *(const bf16x8*)(vp0);
    vv[0][1] = *(const bf16x8*)(vp1);
    vv[0][2] = *(const bf16x8*)(vp0 + 32);
    vv[0][3] = *(const bf16x8*)(vp1 + 32);
    __syncthreads();
    bf16x8 afrag[16];
#pragma unroll
    for (int mt = 0; mt < 16; ++mt)
        afrag[mt] = *(const bf16x8*)&sts[(mt * 16 + l15) * 40 + quad * 8];
    __syncthreads();                          // sts dead; Es may now overwrite
    bf16x8 onesf;
    { short o = (l15 == 0) ? (short)0x3F80 : (short)0;
      onesf = bf16x8{o, o, o, o, o, o, o, o}; }

    f32x4 occ[4][3];
#pragma unroll
    for (int i = 0; i < 4; ++i)
#pragma unroll
        for (int j = 0; j < 3; ++j) occ[i][j] = f32x4{0.f,0.f,0.f,0.f};

#pragma unroll
    for (int sub = 0; sub < 4; ++sub) {
#pragma unroll
        for (int mt = 0; mt < 16; ++mt) {
            f32x4 s = __builtin_amdgcn_mfma_f32_16x16x32_bf16(afrag[mt], kfs[sub], f32x4{0.f,0.f,0.f,0.f}, 0, 0, 0);
#pragma unroll
            for (int r = 0; r < 4; ++r)
                Es[(mt * 16 + quad * 4 + r) * 72 + 16 * w + l15] =
                    __float2bfloat16(__expf(s[r] * SCALE));
        }
        if (sub < 3) {                        // prefetch sub+1 (crosses barrier)
            kfs[sub + 1]   = *(const bf16x8*)(kfp + (long)(sub + 1) * 64 * 512);
            vv[sub + 1][0] = *(const bf16x8*)(vp0 + (sub + 1) * 64);
            vv[sub + 1][1] = *(const bf16x8*)(vp1 + (sub + 1) * 64);
            vv[sub + 1][2] = *(const bf16x8*)(vp0 + (sub + 1) * 64 + 32);
            vv[sub + 1][3] = *(const bf16x8*)(vp1 + (sub + 1) * 64 + 32);
        }
        __syncthreads();
#pragma unroll
        for (int ks = 0; ks < 2; ++ks) {
            bf16x8 bf0 = vv[sub][2 * ks + 0];
            bf16x8 bf1 = vv[sub][2 * ks + 1];
#pragma unroll
            for (int mi = 0; mi < 4; ++mi) {
                bf16x8 af = *(const bf16x8*)&Es[(64 * w + mi * 16 + l15) * 72 + ks * 32 + quad * 8];
                occ[mi][0] = __builtin_amdgcn_mfma_f32_16x16x32_bf16(af, bf0, occ[mi][0], 0, 0, 0);
                occ[mi][1] = __builtin_amdgcn_mfma_f32_16x16x32_bf16(af, bf1, occ[mi][1], 0, 0, 0);
                occ[mi][2] = __builtin_amdgcn_mfma_f32_16x16x32_bf16(af, onesf, occ[mi][2], 0, 0, 0);
            }
        }
        __syncthreads();
    }
    // transpose partials through LDS (Es dead): tb[col][m], pitch 264 bf16
    __hip_bfloat16* tb = Es;
#pragma unroll
    for (int mi = 0; mi < 4; ++mi)
#pragma unroll
        for (int jt = 0; jt < 3; ++jt) {
            if (jt == 2 && l15 != 0) continue;
            int col = jt * 16 + l15;
#pragma unroll
            for (int r = 0; r < 4; ++r) {
                int m = 64 * w + mi * 16 + quad * 4 + r;
                tb[col * 264 + m] = __float2bfloat16(occ[mi][jt][r]);
            }
        }
    __syncthreads();
    // coalesced global write: 33 rows x 256 bf16 = 4224 ints
    int* og = (int*)(opart) + (long)(chunk * 32 + bh) * 4224;
    const int* tbi = (const int*)tb;
#pragma unroll
    for (int i = 0; i < 17; ++i) {
        int idx = t + i * 256;
        if (idx < 4224) {
            int row = idx >> 7, off = idx & 127;
            og[idx] = tbi[row * 132 + off];
        }
    }
}

// Merge stage-1 partials -> sout_bf[bh][d][m]  (coalesced bf16 reads)
__global__ __launch_bounds__(256)
void merge1_kernel(const __hip_bfloat16* __restrict__ opart, __hip_bfloat16* __restrict__ sout)
{
    int t = blockIdx.x * 256 + threadIdx.x;   // 262144
    int m = t & 255;
    int d = (t >> 8) & 31;
    int bh = t >> 13;
    float num = 0.f, den = 0.f;
    for (int ch = 0; ch < 16; ++ch) {
        long base = (long)((ch * 32 + bh) * 33) * 256 + m;
        num += (float)opart[base + (long)d * 256];
        den += (float)opart[base + 32 * 256];
    }
    sout[(long)bh * 8192 + d * 256 + m] = __float2bfloat16(num / den);
}

// ---------------------------------------------------------------------------
// Stage-2 MFMA attention + lepe add.  o_t aliases Es2 (dead after PV reads,
// barrier-separated) -> 50.7KB LDS, 3 blocks/CU.  qf pipelined one sub ahead.
__global__ __launch_bounds__(256)
void stage2_mfma(const __hip_bfloat16* __restrict__ qk_nc,
                 const __hip_bfloat16* __restrict__ st_md,
                 const __hip_bfloat16* __restrict__ sout_bf,
                 const __hip_bfloat16* __restrict__ lepe_cn,
                 float* __restrict__ out)
{
    __shared__ __align__(16) char smem[50688];
    __hip_bfloat16* Es2 = (__hip_bfloat16*)smem;            // 64*264*2 = 33792
    __hip_bfloat16* sos = (__hip_bfloat16*)(smem + 33792);  // 32*264*2 = 16896
    float* o_t = (float*)smem;                              // alias Es2 (8704 B)
    const int chunk = blockIdx.x, bh = blockIdx.y;
    const int b = bh >> 3, h = bh & 7;
    const int t = threadIdx.x, lane = t & 63, w = t >> 6;
    const int l15 = lane & 15, quad = lane >> 4;
    const int n0 = chunk * 256;

    {
        int row = t >> 3, seg = t & 7;
        const int4* src = (const int4*)(sout_bf + (long)bh * 8192 + row * 256 + seg * 32);
        int4* dst = (int4*)&sos[row * 264 + seg * 32];
        dst[0] = src[0]; dst[1] = src[1]; dst[2] = src[2]; dst[3] = src[3];
    }
    bf16x8 stfrag[4];
#pragma unroll
    for (int mt = 0; mt < 4; ++mt)
        stfrag[mt] = *(const bf16x8*)(st_md
            + ((long)(b * 256 + 64 * w + mt * 16 + l15)) * 256 + h * 32 + quad * 8);
    const __hip_bfloat16* qfp = qk_nc + ((long)b * 4096 + n0 + l15) * 512 + h * 32 + quad * 8;
    bf16x8 qq[4][4];
#pragma unroll
    for (int nt = 0; nt < 4; ++nt)
        qq[0][nt] = *(const bf16x8*)(qfp + (long)(nt * 16) * 512);
    bf16x8 onesf;
    { short o = (l15 == 0) ? (short)0x3F80 : (short)0;
      onesf = bf16x8{o, o, o, o, o, o, o, o}; }
    __syncthreads();

#pragma unroll
    for (int sub = 0; sub < 4; ++sub) {
        const int nbase = n0 + sub * 64;
#pragma unroll
        for (int nt = 0; nt < 4; ++nt) {
            bf16x8 qf = qq[sub][nt];
#pragma unroll
            for (int mt = 0; mt < 4; ++mt) {
                f32x4 s = __builtin_amdgcn_mfma_f32_16x16x32_bf16(qf, stfrag[mt], f32x4{0.f,0.f,0.f,0.f}, 0, 0, 0);
#pragma unroll
                for (int r = 0; r < 4; ++r)
                    Es2[(nt * 16 + quad * 4 + r) * 264 + 64 * w + mt * 16 + l15] =
                        __float2bfloat16(__expf(s[r] * SCALE));
            }
        }
        if (sub < 3) {                        // prefetch sub+1 (crosses barrier)
#pragma unroll
            for (int nt = 0; nt < 4; ++nt)
                qq[sub + 1][nt] = *(const bf16x8*)(qfp + (long)((sub + 1) * 64 + nt * 16) * 512);
        }
        __syncthreads();
        f32x4 o0 = {0.f,0.f,0.f,0.f}, o1 = o0, o2 = o0;
#pragma unroll
        for (int ks = 0; ks < 8; ++ks) {
            bf16x8 af = *(const bf16x8*)&Es2[(16 * w + l15) * 264 + ks * 32 + quad * 8];
            bf16x8 b0 = *(const bf16x8*)&sos[(l15) * 264 + ks * 32 + quad * 8];
            bf16x8 b1 = *(const bf16x8*)&sos[(16 + l15) * 264 + ks * 32 + quad * 8];
            o0 = __builtin_amdgcn_mfma_f32_16x16x32_bf16(af, b0, o0, 0, 0, 0);
            o1 = __builtin_amdgcn_mfma_f32_16x16x32_bf16(af, b1, o1, 0, 0, 0);
            o2 = __builtin_amdgcn_mfma_f32_16x16x32_bf16(af, onesf, o2, 0, 0, 0);
        }
        __syncthreads();                      // Es2 dead -> o_t may overwrite
#pragma unroll
        for (int r = 0; r < 4; ++r) {
            float den = __shfl(o2[r], lane & 48);
            float inv = 1.f / den;
            o_t[(l15) * 68 + 16 * w + quad * 4 + r]      = o0[r] * inv;
            o_t[(16 + l15) * 68 + 16 * w + quad * 4 + r] = o1[r] * inv;
        }
        __syncthreads();
        {
            int row = t >> 3, coff = (t & 7) * 8;
            long gb = ((long)(b * 256 + h * 32 + row)) * 4096 + nbase + coff;
            int4 lp4 = *(const int4*)(lepe_cn + gb);
            const __hip_bfloat16* lp = (const __hip_bfloat16*)&lp4;
            const float* sp = &o_t[row * 68 + coff];
            float4 r0, r1;
            r0.x = sp[0] + (float)lp[0]; r0.y = sp[1] + (float)lp[1];
            r0.z = sp[2] + (float)lp[2]; r0.w = sp[3] + (float)lp[3];
            r1.x = sp[4] + (float)lp[4]; r1.y = sp[5] + (float)lp[5];
            r1.z = sp[6] + (float)lp[6]; r1.w = sp[7] + (float)lp[7];
            *(float4*)(out + gb)     = r0;
            *(float4*)(out + gb + 4) = r1;
        }
        __syncthreads();                      // o_t consumed before next Es2 write
    }
}

// ---------------------------------------------------------------------------
extern "C" void kernel_launch(void* const* d_in, const int* in_sizes, int n_in,
                              void* d_out, int out_size, void* d_ws, size_t ws_size,
                              hipStream_t stream)
{
    const float* x    = (const float*)d_in[0];
    const float* aff  = (const float*)d_in[1];
    const float* nw   = (const float*)d_in[2];
    const float* nb   = (const float*)d_in[3];
    const float* Wq   = (const float*)d_in[4];
    const float* Wk   = (const float*)d_in[5];
    const float* Wv   = (const float*)d_in[6];
    const float* Wsp  = (const float*)d_in[7];
    const float* lw   = (const float*)d_in[8];
    const float* lb   = (const float*)d_in[9];
    float* out = (float*)d_out;

    float* ws = (float*)d_ws;
    const long P = PLANE;
    __hip_bfloat16* qk_nc  = (__hip_bfloat16*)(ws);           // [b][n][512] bf16 (16.8MB)
    __hip_bfloat16* v_cn   = (__hip_bfloat16*)(ws + 4 * P);   // [b][c][n]
    __hip_bfloat16* xn_cn  = (__hip_bfloat16*)(ws + 6 * P);
    __hip_bfloat16* xn_nc  = (__hip_bfloat16*)(ws + 8 * P);
    __hip_bfloat16* lepe_cn= (__hip_bfloat16*)(ws + 10 * P);
    float* stoken_part = ws + 14 * P;                          // 32 x 65536 f32
    __hip_bfloat16* opart = (__hip_bfloat16*)(ws + 16 * P);    // 16*32*33*256 bf16
    float* tail        = ws + 16 * P + 2162688;
    __hip_bfloat16* wbf       = (__hip_bfloat16*)tail;
    __hip_bfloat16* st_md     = (__hip_bfloat16*)(tail + 262144);
    __hip_bfloat16* sout_bf   = (__hip_bfloat16*)(tail + 393216);
    float* rs_part = tail + 525312;

    // 1. fused LayerNorm (register-resident) + weight casts
    ln_fused_kernel<<<260, 512, 0, stream>>>(x, nw, nb, Wq, Wk, Wv, Wsp,
                                             xn_cn, xn_nc, wbf);
    // 2. mega1: stoken (staged K-loop) + q/k + v (128x128 one-shot)
    mega1_kernel<<<896, 256, 0, stream>>>(aff, xn_cn, xn_nc, wbf,
                                          qk_nc, v_cn, stoken_part, rs_part);
    // 3. stmd (64 blocks) + lepe conv (512 blocks) — fills idle CUs
    stmd_lepe_kernel<<<576, 256, 0, stream>>>(stoken_part, wbf + 3 * 65536,
                                              st_md, rs_part,
                                              v_cn, lw, lb, lepe_cn);
    // 4. stage-1 attention partials (36.9KB LDS, v/kf pipelined)
    mega2_kernel<<<512, 256, 0, stream>>>(qk_nc, v_cn, st_md, opart);
    // 5. merge -> sout_bf
    merge1_kernel<<<1024, 256, 0, stream>>>(opart, sout_bf);
    // 6. stage-2 attention (50.7KB LDS, qf pipelined) + lepe add -> d_out
    stage2_mfma<<<dim3(16, 32), 256, 0, stream>>>(qk_nc, st_md, sout_bf, lepe_cn, out);
}

// Round 8
// 187.564 us; speedup vs baseline: 1.1527x; 1.0095x over previous
//
#include <hip/hip_runtime.h>
#include <hip/hip_bf16.h>

#define BATCH 4
#define CCH   256
#define HWHW  4096
#define NSP   256
#define NHEAD 8
#define SCALE 0.17677669529663689f
#define PLANE 1048576L

typedef short bf16x8 __attribute__((ext_vector_type(8)));
typedef short bf16x4 __attribute__((ext_vector_type(4)));
typedef float f32x4  __attribute__((ext_vector_type(4)));

__device__ __forceinline__ short f2bs(float f) {
    __hip_bfloat16 h = __float2bfloat16(f);
    return *(short*)&h;
}
__device__ __forceinline__ bf16x8 cvt8(float4 a, float4 b) {
    bf16x8 p;
    p[0] = f2bs(a.x); p[1] = f2bs(a.y); p[2] = f2bs(a.z); p[3] = f2bs(a.w);
    p[4] = f2bs(b.x); p[5] = f2bs(b.y); p[6] = f2bs(b.z); p[7] = f2bs(b.w);
    return p;
}
// async global->LDS, 16B per lane; LDS dest = base + lane*16 (wave-uniform base)
__device__ __forceinline__ void gll16(const __hip_bfloat16* g, __hip_bfloat16* l) {
    __builtin_amdgcn_global_load_lds(
        (const __attribute__((address_space(1))) unsigned int*)(const void*)g,
        (__attribute__((address_space(3))) unsigned int*)(void*)l,
        16, 0, 0);
}

// ---------------------------------------------------------------------------
// Fused LayerNorm -> xn_cn [b][c][n] + xn_nc [b][n][c] (bf16), register-
// resident: 512 thr/block, thread owns 8 channels x 4 pixels. Blocks 256..259: W casts.
__global__ __launch_bounds__(512)
void ln_fused_kernel(const float* __restrict__ x, const float* __restrict__ w,
                     const float* __restrict__ bb,
                     const float* __restrict__ Wq, const float* __restrict__ Wk,
                     const float* __restrict__ Wv, const float* __restrict__ Wsp,
                     __hip_bfloat16* __restrict__ xn_cn,
                     __hip_bfloat16* __restrict__ xn_nc,
                     __hip_bfloat16* __restrict__ wbf)
{
    __shared__ float ps[32][64], pss[32][64];
    __shared__ float mus[64], rstds[64];
    __shared__ float wls[256], bls[256];
    int blk = blockIdx.x;
    int t = threadIdx.x;
    if (blk >= 256) {                        // weight casts
        int sel = blk - 256;
        const float* src = (sel == 0) ? Wq : (sel == 1) ? Wk : (sel == 2) ? Wv : Wsp;
        __hip_bfloat16* dst = wbf + sel * 65536;
        for (int i = t * 4; i < 65536; i += 2048) {
            float4 f = *(const float4*)(src + i);
            __hip_bfloat16 p[4];
            p[0] = __float2bfloat16(f.x); p[1] = __float2bfloat16(f.y);
            p[2] = __float2bfloat16(f.z); p[3] = __float2bfloat16(f.w);
            *(int2*)(dst + i) = *(int2*)p;
        }
        return;
    }
    int b = blk >> 6;
    int n0 = (blk & 63) * 64;
    int pg = t & 15;                         // pixel group: 4 pixels
    int cq = t >> 4;                         // channel group: 8 channels
    if (t < 256) { wls[t] = w[t]; bls[t] = bb[t]; }

    const float* xp = x + ((long)(b * CCH + cq * 8)) * HWHW + n0 + pg * 4;
    float4 v[8];
#pragma unroll
    for (int i = 0; i < 8; ++i) v[i] = *(const float4*)(xp + (long)i * HWHW);
    float4 s = {0.f,0.f,0.f,0.f}, ss = {0.f,0.f,0.f,0.f};
#pragma unroll
    for (int i = 0; i < 8; ++i) {
        s.x += v[i].x; s.y += v[i].y; s.z += v[i].z; s.w += v[i].w;
        ss.x += v[i].x * v[i].x; ss.y += v[i].y * v[i].y;
        ss.z += v[i].z * v[i].z; ss.w += v[i].w * v[i].w;
    }
    *(float4*)&ps[cq][pg * 4]  = s;
    *(float4*)&pss[cq][pg * 4] = ss;
    __syncthreads();
    if (t < 64) {
        float S = 0.f, SS = 0.f;
#pragma unroll
        for (int q = 0; q < 32; ++q) { S += ps[q][t]; SS += pss[q][t]; }
        float mu = S * (1.f / 256.f);
        float var = SS * (1.f / 256.f) - mu * mu;
        mus[t] = mu; rstds[t] = rsqrtf(var + 1e-6f);
    }
    __syncthreads();
    float4 mu4 = *(float4*)&mus[pg * 4];
    float4 rs4 = *(float4*)&rstds[pg * 4];

    bf16x8 pk[4];                            // [pixel j][channel i]
#pragma unroll
    for (int i = 0; i < 8; ++i) {
        int c = cq * 8 + i;
        float wc = wls[c], bc = bls[c];
        short h0 = f2bs((v[i].x - mu4.x) * rs4.x * wc + bc);
        short h1 = f2bs((v[i].y - mu4.y) * rs4.y * wc + bc);
        short h2 = f2bs((v[i].z - mu4.z) * rs4.z * wc + bc);
        short h3 = f2bs((v[i].w - mu4.w) * rs4.w * wc + bc);
        pk[0][i] = h0; pk[1][i] = h1; pk[2][i] = h2; pk[3][i] = h3;
        bf16x4 q; q[0] = h0; q[1] = h1; q[2] = h2; q[3] = h3;
        *(bf16x4*)(xn_cn + ((long)(b * CCH + c)) * HWHW + n0 + pg * 4) = q;
    }
#pragma unroll
    for (int j = 0; j < 4; ++j)
        *(bf16x8*)(xn_nc + ((long)b * HWHW + n0 + pg * 4 + j) * CCH + cq * 8) = pk[j];
}

// ---------------------------------------------------------------------------
// K=256 one-shot 128x128 GEMM: stage full A-tile (128x256 bf16 = 64KB) into
// LDS once via 64 gll16 in slab layout [rowtile][kslot], ONE barrier, then
// each wave computes a 64x64 quadrant: 4x4 accs = 128 MFMAs, B fragments
// direct-from-global with one-deep register prefetch.  Bit-identical k order.
__device__ __forceinline__ void gemm_k256_128(
    const __hip_bfloat16* __restrict__ A, const __hip_bfloat16* __restrict__ B,
    __hip_bfloat16* __restrict__ C, int bx, int by, int bz,
    int N, long aStrideZ, long bStrideZ, long cStrideZ,
    __hip_bfloat16* __restrict__ Asm)
{
    const int K = 256;
    const int t = threadIdx.x, lane = t & 63, w = t >> 6;
    const int l15 = lane & 15, quad = lane >> 4;
    const int Mt = by * 128, Nt = bx * 128;
    {
        const __hip_bfloat16* aBase = A + (long)bz * aStrideZ
            + (long)(Mt + l15) * K + quad * 8;
#pragma unroll
        for (int p = 0; p < 16; ++p) {
            const int rt = w * 2 + (p >> 3), s = p & 7;
            gll16(aBase + (long)(rt * 16) * K + s * 32, Asm + (rt * 8 + s) * 512);
        }
    }
    const int wm2 = w & 1, wn2 = w >> 1;
    const __hip_bfloat16* bBase = B + (long)bz * bStrideZ
        + (long)(Nt + wn2 * 64 + l15) * K + quad * 8;

    f32x4 acc[4][4];
#pragma unroll
    for (int mi = 0; mi < 4; ++mi)
#pragma unroll
        for (int nj = 0; nj < 4; ++nj) acc[mi][nj] = f32x4{0.f,0.f,0.f,0.f};

    bf16x8 bEv[4], bOd[4];
#pragma unroll
    for (int nj = 0; nj < 4; ++nj)
        bEv[nj] = *(const bf16x8*)(bBase + (long)(nj * 16) * K);
    __syncthreads();                          // A tile ready
#pragma unroll
    for (int sp = 0; sp < 4; ++sp) {
        const int s0 = 2 * sp, s1 = 2 * sp + 1;
#pragma unroll
        for (int nj = 0; nj < 4; ++nj)       // prefetch odd slot
            bOd[nj] = *(const bf16x8*)(bBase + (long)(nj * 16) * K + s1 * 32);
#pragma unroll
        for (int mi = 0; mi < 4; ++mi) {
            bf16x8 a = *(const bf16x8*)&Asm[((wm2 * 4 + mi) * 8 + s0) * 512 + lane * 8];
            acc[mi][0] = __builtin_amdgcn_mfma_f32_16x16x32_bf16(a, bEv[0], acc[mi][0], 0, 0, 0);
            acc[mi][1] = __builtin_amdgcn_mfma_f32_16x16x32_bf16(a, bEv[1], acc[mi][1], 0, 0, 0);
            acc[mi][2] = __builtin_amdgcn_mfma_f32_16x16x32_bf16(a, bEv[2], acc[mi][2], 0, 0, 0);
            acc[mi][3] = __builtin_amdgcn_mfma_f32_16x16x32_bf16(a, bEv[3], acc[mi][3], 0, 0, 0);
        }
        if (sp < 3) {
#pragma unroll
            for (int nj = 0; nj < 4; ++nj)   // prefetch next even slot
                bEv[nj] = *(const bf16x8*)(bBase + (long)(nj * 16) * K + (s0 + 2) * 32);
        }
#pragma unroll
        for (int mi = 0; mi < 4; ++mi) {
            bf16x8 a = *(const bf16x8*)&Asm[((wm2 * 4 + mi) * 8 + s1) * 512 + lane * 8];
            acc[mi][0] = __builtin_amdgcn_mfma_f32_16x16x32_bf16(a, bOd[0], acc[mi][0], 0, 0, 0);
            acc[mi][1] = __builtin_amdgcn_mfma_f32_16x16x32_bf16(a, bOd[1], acc[mi][1], 0, 0, 0);
            acc[mi][2] = __builtin_amdgcn_mfma_f32_16x16x32_bf16(a, bOd[2], acc[mi][2], 0, 0, 0);
            acc[mi][3] = __builtin_amdgcn_mfma_f32_16x16x32_bf16(a, bOd[3], acc[mi][3], 0, 0, 0);
        }
    }
#pragma unroll
    for (int mi = 0; mi < 4; ++mi)
#pragma unroll
        for (int nj = 0; nj < 4; ++nj)
#pragma unroll
            for (int r = 0; r < 4; ++r) {
                int m = Mt + wm2 * 64 + mi * 16 + quad * 4 + r;
                int n = Nt + wn2 * 64 + nj * 16 + l15;
                C[(long)bz * cStrideZ + (long)m * N + n] =
                    __float2bfloat16(acc[mi][nj][r]);
            }
}

// ---------------------------------------------------------------------------
// bf16 MFMA NT GEMM body, BK=64 (for large-K / fp32-A cases).
// ASTAGE: 1 = A fp32 reg-convert (prefetched);
//         2 = A = sum of 8 fp32 planes (stride 65536) + fused rowscale (rsl).
// ROWSUM: emit rsPart[z*256+m].  NTL: N-tiles per block.
template <int OUTK, int ASTAGE, bool ROWSUM, int NTL>
__device__ __forceinline__ void gemm_body(
    const void* __restrict__ Av, const __hip_bfloat16* __restrict__ B,
    void* __restrict__ Cptr, int bx, int by, int bz,
    int N, int K, int kChunk, int kShift,
    long aStrideZ, long bStrideZ, long cStrideZ,
    float* __restrict__ rsPart,
    __hip_bfloat16* __restrict__ Asm, __hip_bfloat16* __restrict__ Bsm,
    float* __restrict__ rsl)
{
    int z = bz;
    int b = z >> kShift;
    int ch = z & ((1 << kShift) - 1);
    int t = threadIdx.x;
    int lane = t & 63, w = t >> 6;
    int l15 = lane & 15, quad = lane >> 4;
    int Mt = by * 64, Nt = bx * 64 * NTL;

    if (ASTAGE == 2 && t < 64) {             // fused rowsum reduce (8 chunks)
        float s = 0.f;
#pragma unroll
        for (int pl = 0; pl < 8; ++pl) s += rsPart[((b * 8 + pl) << 8) + Mt + t];
        rsl[t] = s;
    }

    long aOff = (long)b * aStrideZ + (long)ch * kChunk
        + (long)(Mt + w * 16 + l15) * K + quad * 8;
    const float* aSrcF = (const float*)Av + aOff;
    const __hip_bfloat16* bSrc = B + (long)b * bStrideZ + (long)ch * kChunk
        + (long)(Nt + w * 16 + l15) * K + quad * 8;

    f32x4 acc[NTL][2][2];
#pragma unroll
    for (int nt = 0; nt < NTL; ++nt)
#pragma unroll
        for (int i = 0; i < 2; ++i)
#pragma unroll
            for (int j = 0; j < 2; ++j) acc[nt][i][j] = f32x4{0.f,0.f,0.f,0.f};
    f32x4 rs0 = {0.f,0.f,0.f,0.f}, rs1 = rs0;
    bf16x8 onesf;
    { short o = (l15 == 0) ? (short)0x3F80 : (short)0;
      onesf = bf16x8{o, o, o, o, o, o, o, o}; }
    int wm = (w & 1) * 2, wn = (w >> 1) * 2;

    float4 pf0, pf1, pf2, pf3;
    if (ASTAGE == 1) {
        pf0 = *(const float4*)(aSrcF);      pf1 = *(const float4*)(aSrcF + 4);
        pf2 = *(const float4*)(aSrcF + 32); pf3 = *(const float4*)(aSrcF + 36);
    }

    const bf16x8* AsmU = (const bf16x8*)Asm;
    const bf16x8* BsmU = (const bf16x8*)Bsm;

    for (int k0 = 0; k0 < kChunk; k0 += 64) {
        // ---- stage A ----
        if (ASTAGE == 1) {
            *(bf16x8*)&Asm[t * 8]        = cvt8(pf0, pf1);
            *(bf16x8*)&Asm[2048 + t * 8] = cvt8(pf2, pf3);
        } else {                              // 8-plane fp32 sum
#pragma unroll
            for (int kh = 0; kh < 2; ++kh) {
                float4 s0 = {0.f,0.f,0.f,0.f}, s1 = {0.f,0.f,0.f,0.f};
#pragma unroll
                for (int pl = 0; pl < 8; ++pl) {
                    const float* p = aSrcF + (long)pl * 65536 + k0 + kh * 32;
                    float4 u0 = *(const float4*)p, u1 = *(const float4*)(p + 4);
                    s0.x += u0.x; s0.y += u0.y; s0.z += u0.z; s0.w += u0.w;
                    s1.x += u1.x; s1.y += u1.y; s1.z += u1.z; s1.w += u1.w;
                }
                *(bf16x8*)&Asm[kh * 2048 + t * 8] = cvt8(s0, s1);
            }
        }
        // ---- stage B (bf16, async direct-to-LDS) ----
#pragma unroll
        for (int nt = 0; nt < NTL; ++nt) {
            gll16(bSrc + (long)nt * 64 * K + k0,      Bsm + nt * 4096 + w * 512);
            gll16(bSrc + (long)nt * 64 * K + k0 + 32, Bsm + nt * 4096 + 2048 + w * 512);
        }
        __syncthreads();
        if (ASTAGE == 1 && k0 + 64 < kChunk) {   // prefetch next A chunk
            const float* nx = aSrcF + k0 + 64;
            pf0 = *(const float4*)nx;        pf1 = *(const float4*)(nx + 4);
            pf2 = *(const float4*)(nx + 32); pf3 = *(const float4*)(nx + 36);
        }
        // ---- MFMA ----
#pragma unroll
        for (int kh = 0; kh < 2; ++kh) {
            bf16x8 a0 = AsmU[kh * 256 + wm * 64 + lane];
            bf16x8 a1 = AsmU[kh * 256 + (wm + 1) * 64 + lane];
            if (ROWSUM) {
                rs0 = __builtin_amdgcn_mfma_f32_16x16x32_bf16(a0, onesf, rs0, 0, 0, 0);
                rs1 = __builtin_amdgcn_mfma_f32_16x16x32_bf16(a1, onesf, rs1, 0, 0, 0);
            }
#pragma unroll
            for (int nt = 0; nt < NTL; ++nt) {
                bf16x8 b0 = BsmU[nt * 512 + kh * 256 + wn * 64 + lane];
                bf16x8 b1 = BsmU[nt * 512 + kh * 256 + (wn + 1) * 64 + lane];
                acc[nt][0][0] = __builtin_amdgcn_mfma_f32_16x16x32_bf16(a0, b0, acc[nt][0][0], 0, 0, 0);
                acc[nt][0][1] = __builtin_amdgcn_mfma_f32_16x16x32_bf16(a0, b1, acc[nt][0][1], 0, 0, 0);
                acc[nt][1][0] = __builtin_amdgcn_mfma_f32_16x16x32_bf16(a1, b0, acc[nt][1][0], 0, 0, 0);
                acc[nt][1][1] = __builtin_amdgcn_mfma_f32_16x16x32_bf16(a1, b1, acc[nt][1][1], 0, 0, 0);
            }
        }
        __syncthreads();
    }
    if (ROWSUM && bx == 0 && (w >> 1) == 0 && l15 == 0) {
#pragma unroll
        for (int r = 0; r < 4; ++r) {
            rsPart[(long)z * 256 + Mt + wm * 16 + quad * 4 + r]       = rs0[r];
            rsPart[(long)z * 256 + Mt + (wm + 1) * 16 + quad * 4 + r] = rs1[r];
        }
    }
#pragma unroll
    for (int nt = 0; nt < NTL; ++nt)
#pragma unroll
        for (int i = 0; i < 2; ++i)
#pragma unroll
            for (int j = 0; j < 2; ++j)
#pragma unroll
                for (int r = 0; r < 4; ++r) {
                    int m = Mt + (wm + i) * 16 + quad * 4 + r;
                    int n = Nt + nt * 64 + (wn + j) * 16 + l15;
                    float val = acc[nt][i][j][r];
                    if (ASTAGE == 2) val /= (rsl[m - Mt] + 1e-16f);
                    long off = (long)z * cStrideZ + (long)m * N + n;
                    if (OUTK == 0) ((float*)Cptr)[off] = val;
                    else ((__hip_bfloat16*)Cptr)[off] = __float2bfloat16(val);
                }
}

// mega1: stoken [0,128) | q+k 128-tile [128,640) | v 128-tile [640,896)
__global__ __launch_bounds__(256, 2)
void mega1_kernel(const float* __restrict__ aff,
                  const __hip_bfloat16* __restrict__ xn_cn,
                  const __hip_bfloat16* __restrict__ xn_nc,
                  const __hip_bfloat16* __restrict__ wbf,
                  __hip_bfloat16* __restrict__ qk_nc,
                  __hip_bfloat16* __restrict__ v_cn,
                  float* __restrict__ stoken_part,
                  float* __restrict__ rs_part)
{
    __shared__ __align__(16) char smem[65536];
    __hip_bfloat16* Asm = (__hip_bfloat16*)smem;            // stoken: 8KB
    __hip_bfloat16* Bsm = (__hip_bfloat16*)(smem + 8192);   // stoken: 32KB
    __hip_bfloat16* A128 = (__hip_bfloat16*)smem;           // 128-tile: 64KB
    int blk = blockIdx.x;
    if (blk < 128) {          // stoken partials; same-z (shared B) 32 apart
        int i = blk;
        gemm_body<0, 1, true, 4>(aff, xn_cn, stoken_part,
            0, i >> 5, i & 31, 256, 4096, 512, 3,
            PLANE, PLANE, 65536L, rs_part, Asm, Bsm, nullptr);
    } else if (blk < 640) {   // fused q+k: A=xn_nc tile shared by bx=0..3
        int i = blk - 128;
        int bx = i >> 7, rem = i & 127;
        gemm_k256_128(xn_nc, wbf, qk_nc,
            bx, rem >> 2, rem & 3, 512, PLANE, 0L, 2 * PLANE, A128);
    } else {                  // v_cn: B=xn_nc tile shared by by=0..1
        int i = blk - 640;
        int by = i >> 7, rem = i & 127;
        gemm_k256_128(wbf + 2 * 65536, xn_nc, v_cn,
            rem >> 2, by, rem & 3, 4096, 0L, PLANE, PLANE, A128);
    }
}

// ---------------------------------------------------------------------------
// Depthwise 3x3 conv + scramble-transpose (device fn; smem carved by caller).
__device__ __forceinline__
void lepe_dev(char* smem, int bx, int cy, int b,
              const __hip_bfloat16* __restrict__ v_cn,
              const float* __restrict__ lw, const float* __restrict__ lb,
              __hip_bfloat16* __restrict__ lepe_cn)
{
    __hip_bfloat16* in_t    = (__hip_bfloat16*)smem;            // 32*384*2 = 24576
    __hip_bfloat16* tile_bf = (__hip_bfloat16*)(smem + 24576);  // 256*33*2 = 16896
    float* wls = (float*)(smem + 41472);                        // 288*4
    float* bls = (float*)(smem + 42624);                        // 32*4
    const int c0 = cy * 32;
    const int t = threadIdx.x;
    const int n0 = bx * 256, r0 = bx * 4;

    for (int i = t; i < 288; i += 256) wls[i] = lw[c0 * 9 + i];
    if (t < 32)  bls[t] = lb[c0 + t];
#pragma unroll
    for (int i = 0; i < 6; ++i) {
        int vi = t + i * 256;
        int ch = vi / 48;
        int off = (vi % 48) * 8;
        int g = (r0 - 1) * 64 + off;
        int4 val = {0, 0, 0, 0};
        if ((unsigned)g < 4096u)
            val = *(const int4*)(v_cn + (((long)(b * CCH + c0 + ch)) << 12) + g);
        *(int4*)&in_t[ch * 384 + off] = val;
    }
    __syncthreads();

    const int lane = t & 63, w = t >> 6;
#pragma unroll
    for (int i = 0; i < 8; ++i) {
        int ch = w * 8 + i;
        float cr[6], lf[6], rf[6];
#pragma unroll
        for (int rr = 0; rr < 6; ++rr) {
            cr[rr] = (float)in_t[ch * 384 + rr * 64 + lane];
            float lv = __shfl_up(cr[rr], 1);
            float rv = __shfl_down(cr[rr], 1);
            lf[rr] = (lane == 0) ? 0.f : lv;
            rf[rr] = (lane == 63) ? 0.f : rv;
        }
        float w0 = wls[ch*9+0], w1 = wls[ch*9+1], w2 = wls[ch*9+2];
        float w3 = wls[ch*9+3], w4 = wls[ch*9+4], w5 = wls[ch*9+5];
        float w6 = wls[ch*9+6], w7 = wls[ch*9+7], w8 = wls[ch*9+8];
        float bias = bls[ch];
#pragma unroll
        for (int r = 0; r < 4; ++r) {
            float acc = bias
                + lf[r]   * w0 + cr[r]   * w1 + rf[r]   * w2
                + lf[r+1] * w3 + cr[r+1] * w4 + rf[r+1] * w5
                + lf[r+2] * w6 + cr[r+2] * w7 + rf[r+2] * w8;
            tile_bf[(r * 64 + lane) * 33 + ch] = __float2bfloat16(acc);
        }
    }
    __syncthreads();
#pragma unroll
    for (int i = 0; i < 32; ++i) {
        int idx = t + i * 256;
        int nl = idx >> 5, cj = idx & 31;
        int sp = n0 + nl;
        lepe_cn[((long)(b * CCH + (sp >> 4)) << 12) + (nl & 15) * 256 + c0 + cj] =
            tile_bf[nl * 33 + cj];
    }
}

// stmd_lepe: stmd [0,64) | lepe [64,576) — both depend only on mega1 outputs.
__global__ __launch_bounds__(256)
void stmd_lepe_kernel(const float* __restrict__ part,
                      const __hip_bfloat16* __restrict__ wsp,
                      __hip_bfloat16* __restrict__ st_md,
                      float* __restrict__ rs_part,
                      const __hip_bfloat16* __restrict__ v_cn,
                      const float* __restrict__ lw, const float* __restrict__ lb,
                      __hip_bfloat16* __restrict__ lepe_cn)
{
    __shared__ __align__(16) char smem[43008];
    int blk = blockIdx.x;
    if (blk < 64) {
        __hip_bfloat16* Asm = (__hip_bfloat16*)smem;
        __hip_bfloat16* Bsm = (__hip_bfloat16*)(smem + 8192);
        float* rsl = (float*)(smem + 16384);
        int i = blk;
        gemm_body<1, 2, false, 1>(part, wsp, st_md,
            i & 3, (i >> 2) & 3, i >> 4, 256, 256, 256, 0,
            524288L, 0L, 65536L, rs_part, Asm, Bsm, rsl);
    } else {
        int j = blk - 64;
        lepe_dev(smem, j & 15, (j >> 4) & 7, j >> 7, v_cn, lw, lb, lepe_cn);
    }
}

// ---------------------------------------------------------------------------
// Stage-1 MFMA attention partials, m-split: each block handles 128 of the
// 256 m rows -> grid 1024, Es 18.4KB, afrag[8], occ[2][3].  v operands
// early-issued per sub (covered by QK phase); kf 1-deep prefetch.
__global__ __launch_bounds__(256)
void mega2_kernel(const __hip_bfloat16* __restrict__ qk_nc,
                  const __hip_bfloat16* __restrict__ v_cn,
                  const __hip_bfloat16* __restrict__ st_md,
                  __hip_bfloat16* __restrict__ opart)
{
    __shared__ __align__(16) char smem[18432];
    __hip_bfloat16* Es  = (__hip_bfloat16*)smem;            // 128*72*2 = 18432
    __hip_bfloat16* sts = (__hip_bfloat16*)smem;            // alias (10240 B used)
    const int blk = blockIdx.x;
    const int mh = blk & 1;
    const int chunk = (blk >> 1) & 15;
    const int bh = blk >> 5;
    const int b = bh >> 3, h = bh & 7;
    const int t = threadIdx.x, lane = t & 63, w = t >> 6;
    const int l15 = lane & 15, quad = lane >> 4;
    const int n0 = chunk * 256;

    {   // stage st rows [mh*128, +128) x 32 h-cols (2 int4 per thread)
        int row = t >> 1, half = t & 1;
        const int4* src = (const int4*)(st_md
            + ((long)(b * 256 + mh * 128 + row)) * 256 + h * 32 + half * 16);
        int4* dst = (int4*)&sts[row * 40 + half * 16];
        dst[0] = src[0]; dst[1] = src[1];
    }
    const __hip_bfloat16* kfp = qk_nc + ((long)b * 4096 + n0 + 16 * w + l15) * 512 + 256 + h * 32 + quad * 8;
    const __hip_bfloat16* vp0 = v_cn + ((long)(b * 256 + h * 32 + l15)) * 4096 + n0 + quad * 8;
    const __hip_bfloat16* vp1 = vp0 + 16 * 4096;
    bf16x8 kfc = *(const bf16x8*)(kfp);       // sub-0 k fragment
    __syncthreads();
    bf16x8 afrag[8];
#pragma unroll
    for (int mt = 0; mt < 8; ++mt)
        afrag[mt] = *(const bf16x8*)&sts[(mt * 16 + l15) * 40 + quad * 8];
    __syncthreads();                          // sts dead; Es may now overwrite
    bf16x8 onesf;
    { short o = (l15 == 0) ? (short)0x3F80 : (short)0;
      onesf = bf16x8{o, o, o, o, o, o, o, o}; }

    f32x4 occ[2][3];
#pragma unroll
    for (int i = 0; i < 2; ++i)
#pragma unroll
        for (int j = 0; j < 3; ++j) occ[i][j] = f32x4{0.f,0.f,0.f,0.f};

#pragma unroll
    for (int sub = 0; sub < 4; ++sub) {
        // early-issue this sub's v fragments (consumed after barrier)
        bf16x8 vv0 = *(const bf16x8*)(vp0 + sub * 64);
        bf16x8 vv1 = *(const bf16x8*)(vp1 + sub * 64);
        bf16x8 vv2 = *(const bf16x8*)(vp0 + sub * 64 + 32);
        bf16x8 vv3 = *(const bf16x8*)(vp1 + sub * 64 + 32);
#pragma unroll
        for (int mt = 0; mt < 8; ++mt) {
            f32x4 s = __builtin_amdgcn_mfma_f32_16x16x32_bf16(afrag[mt], kfc, f32x4{0.f,0.f,0.f,0.f}, 0, 0, 0);
#pragma unroll
            for (int r = 0; r < 4; ++r)
                Es[(mt * 16 + quad * 4 + r) * 72 + 16 * w + l15] =
                    __float2bfloat16(__expf(s[r] * SCALE));
        }
        if (sub < 3)                          // 1-deep kf prefetch
            kfc = *(const bf16x8*)(kfp + (long)(sub + 1) * 64 * 512);
        __syncthreads();
#pragma unroll
        for (int ks = 0; ks < 2; ++ks) {
            bf16x8 bf0 = (ks == 0) ? vv0 : vv2;
            bf16x8 bf1 = (ks == 0) ? vv1 : vv3;
#pragma unroll
            for (int mi = 0; mi < 2; ++mi) {
                bf16x8 af = *(const bf16x8*)&Es[(32 * w + mi * 16 + l15) * 72 + ks * 32 + quad * 8];
                occ[mi][0] = __builtin_amdgcn_mfma_f32_16x16x32_bf16(af, bf0, occ[mi][0], 0, 0, 0);
                occ[mi][1] = __builtin_amdgcn_mfma_f32_16x16x32_bf16(af, bf1, occ[mi][1], 0, 0, 0);
                occ[mi][2] = __builtin_amdgcn_mfma_f32_16x16x32_bf16(af, onesf, occ[mi][2], 0, 0, 0);
            }
        }
        __syncthreads();
    }
    // transpose partials through LDS (Es dead): tb[col][m_local], pitch 136
    __hip_bfloat16* tb = Es;
#pragma unroll
    for (int mi = 0; mi < 2; ++mi)
#pragma unroll
        for (int jt = 0; jt < 3; ++jt) {
            if (jt == 2 && l15 != 0) continue;
            int col = jt * 16 + l15;
#pragma unroll
            for (int r = 0; r < 4; ++r) {
                int m = 32 * w + mi * 16 + quad * 4 + r;
                tb[col * 136 + m] = __float2bfloat16(occ[mi][jt][r]);
            }
        }
    __syncthreads();
    // coalesced global write: 33 rows x 128 bf16-half = 2112 ints
    int* og = (int*)(opart) + (long)(chunk * 32 + bh) * 4224;
    const int* tbi = (const int*)tb;
#pragma unroll
    for (int i = 0; i < 9; ++i) {
        int idx = t + i * 256;
        if (idx < 2112) {
            int row = idx >> 6, off = idx & 63;
            og[row * 128 + mh * 64 + off] = tbi[row * 68 + off];
        }
    }
}

// Merge stage-1 partials -> sout_bf[bh][d][m]  (coalesced bf16 reads)
__global__ __launch_bounds__(256)
void merge1_kernel(const __hip_bfloat16* __restrict__ opart, __hip_bfloat16* __restrict__ sout)
{
    int t = blockIdx.x * 256 + threadIdx.x;   // 262144
    int m = t & 255;
    int d = (t >> 8) & 31;
    int bh = t >> 13;
    float num = 0.f, den = 0.f;
    for (int ch = 0; ch < 16; ++ch) {
        long base = (long)((ch * 32 + bh) * 33) * 256 + m;
        num += (float)opart[base + (long)d * 256];
        den += (float)opart[base + 32 * 256];
    }
    sout[(long)bh * 8192 + d * 256 + m] = __float2bfloat16(num / den);
}

// ---------------------------------------------------------------------------
// Stage-2 MFMA attention + lepe add, n-split: 32 chunks x 2 subs per block.
// o_t aliases Es2; qf pipelined one sub ahead (qq[2][4]).
__global__ __launch_bounds__(256)
void stage2_mfma(const __hip_bfloat16* __restrict__ qk_nc,
                 const __hip_bfloat16* __restrict__ st_md,
                 const __hip_bfloat16* __restrict__ sout_bf,
                 const __hip_bfloat16* __restrict__ lepe_cn,
                 float* __restrict__ out)
{
    __shared__ __align__(16) char smem[50688];
    __hip_bfloat16* Es2 = (__hip_bfloat16*)smem;            // 64*264*2 = 33792
    __hip_bfloat16* sos = (__hip_bfloat16*)(smem + 33792);  // 32*264*2 = 16896
    float* o_t = (float*)smem;                              // alias Es2 (8704 B)
    const int chunk = blockIdx.x, bh = blockIdx.y;
    const int b = bh >> 3, h = bh & 7;
    const int t = threadIdx.x, lane = t & 63, w = t >> 6;
    const int l15 = lane & 15, quad = lane >> 4;
    const int n0 = chunk * 128;

    {
        int row = t >> 3, seg = t & 7;
        const int4* src = (const int4*)(sout_bf + (long)bh * 8192 + row * 256 + seg * 32);
        int4* dst = (int4*)&sos[row * 264 + seg * 32];
        dst[0] = src[0]; dst[1] = src[1]; dst[2] = src[2]; dst[3] = src[3];
    }
    bf16x8 stfrag[4];
#pragma unroll
    for (int mt = 0; mt < 4; ++mt)
        stfrag[mt] = *(const bf16x8*)(st_md
            + ((long)(b * 256 + 64 * w + mt * 16 + l15)) * 256 + h * 32 + quad * 8);
    const __hip_bfloat16* qfp = qk_nc + ((long)b * 4096 + n0 + l15) * 512 + h * 32 + quad * 8;
    bf16x8 qq[2][4];
#pragma unroll
    for (int nt = 0; nt < 4; ++nt)
        qq[0][nt] = *(const bf16x8*)(qfp + (long)(nt * 16) * 512);
    bf16x8 onesf;
    { short o = (l15 == 0) ? (short)0x3F80 : (short)0;
      onesf = bf16x8{o, o, o, o, o, o, o, o}; }
    __syncthreads();

#pragma unroll
    for (int sub = 0; sub < 2; ++sub) {
        const int nbase = n0 + sub * 64;
#pragma unroll
        for (int nt = 0; nt < 4; ++nt) {
            bf16x8 qf = qq[sub][nt];
#pragma unroll
            for (int mt = 0; mt < 4; ++mt) {
                f32x4 s = __builtin_amdgcn_mfma_f32_16x16x32_bf16(qf, stfrag[mt], f32x4{0.f,0.f,0.f,0.f}, 0, 0, 0);
#pragma unroll
                for (int r = 0; r < 4; ++r)
                    Es2[(nt * 16 + quad * 4 + r) * 264 + 64 * w + mt * 16 + l15] =
                        __float2bfloat16(__expf(s[r] * SCALE));
            }
        }
        if (sub < 1) {                        // prefetch sub+1 (crosses barrier)
#pragma unroll
            for (int nt = 0; nt < 4; ++nt)
                qq[1][nt] = *(const bf16x8*)(qfp + (long)(64 + nt * 16) * 512);
        }
        __syncthreads();
        f32x4 o0 = {0.f,0.f,0.f,0.f}, o1 = o0, o2 = o0;
#pragma unroll
        for (int ks = 0; ks < 8; ++ks) {
            bf16x8 af = *(const bf16x8*)&Es2[(16 * w + l15) * 264 + ks * 32 + quad * 8];
            bf16x8 b0 = *(const bf16x8*)&sos[(l15) * 264 + ks * 32 + quad * 8];
            bf16x8 b1 = *(const bf16x8*)&sos[(16 + l15) * 264 + ks * 32 + quad * 8];
            o0 = __builtin_amdgcn_mfma_f32_16x16x32_bf16(af, b0, o0, 0, 0, 0);
            o1 = __builtin_amdgcn_mfma_f32_16x16x32_bf16(af, b1, o1, 0, 0, 0);
            o2 = __builtin_amdgcn_mfma_f32_16x16x32_bf16(af, onesf, o2, 0, 0, 0);
        }
        __syncthreads();                      // Es2 dead -> o_t may overwrite
#pragma unroll
        for (int r = 0; r < 4; ++r) {
            float den = __shfl(o2[r], lane & 48);
            float inv = 1.f / den;
            o_t[(l15) * 68 + 16 * w + quad * 4 + r]      = o0[r] * inv;
            o_t[(16 + l15) * 68 + 16 * w + quad * 4 + r] = o1[r] * inv;
        }
        __syncthreads();
        {
            int row = t >> 3, coff = (t & 7) * 8;
            long gb = ((long)(b * 256 + h * 32 + row)) * 4096 + nbase + coff;
            int4 lp4 = *(const int4*)(lepe_cn + gb);
            const __hip_bfloat16* lp = (const __hip_bfloat16*)&lp4;
            const float* sp = &o_t[row * 68 + coff];
            float4 r0, r1;
            r0.x = sp[0] + (float)lp[0]; r0.y = sp[1] + (float)lp[1];
            r0.z = sp[2] + (float)lp[2]; r0.w = sp[3] + (float)lp[3];
            r1.x = sp[4] + (float)lp[4]; r1.y = sp[5] + (float)lp[5];
            r1.z = sp[6] + (float)lp[6]; r1.w = sp[7] + (float)lp[7];
            *(float4*)(out + gb)     = r0;
            *(float4*)(out + gb + 4) = r1;
        }
        __syncthreads();                      // o_t consumed before next Es2 write
    }
}

// ---------------------------------------------------------------------------
extern "C" void kernel_launch(void* const* d_in, const int* in_sizes, int n_in,
                              void* d_out, int out_size, void* d_ws, size_t ws_size,
                              hipStream_t stream)
{
    const float* x    = (const float*)d_in[0];
    const float* aff  = (const float*)d_in[1];
    const float* nw   = (const float*)d_in[2];
    const float* nb   = (const float*)d_in[3];
    const float* Wq   = (const float*)d_in[4];
    const float* Wk   = (const float*)d_in[5];
    const float* Wv   = (const float*)d_in[6];
    const float* Wsp  = (const float*)d_in[7];
    const float* lw   = (const float*)d_in[8];
    const float* lb   = (const float*)d_in[9];
    float* out = (float*)d_out;

    float* ws = (float*)d_ws;
    const long P = PLANE;
    __hip_bfloat16* qk_nc  = (__hip_bfloat16*)(ws);           // [b][n][512] bf16 (16.8MB)
    __hip_bfloat16* v_cn   = (__hip_bfloat16*)(ws + 4 * P);   // [b][c][n]
    __hip_bfloat16* xn_cn  = (__hip_bfloat16*)(ws + 6 * P);
    __hip_bfloat16* xn_nc  = (__hip_bfloat16*)(ws + 8 * P);
    __hip_bfloat16* lepe_cn= (__hip_bfloat16*)(ws + 10 * P);
    float* stoken_part = ws + 14 * P;                          // 32 x 65536 f32
    __hip_bfloat16* opart = (__hip_bfloat16*)(ws + 16 * P);    // 16*32*33*256 bf16
    float* tail        = ws + 16 * P + 2162688;
    __hip_bfloat16* wbf       = (__hip_bfloat16*)tail;
    __hip_bfloat16* st_md     = (__hip_bfloat16*)(tail + 262144);
    __hip_bfloat16* sout_bf   = (__hip_bfloat16*)(tail + 393216);
    float* rs_part = tail + 525312;

    // 1. fused LayerNorm (register-resident) + weight casts
    ln_fused_kernel<<<260, 512, 0, stream>>>(x, nw, nb, Wq, Wk, Wv, Wsp,
                                             xn_cn, xn_nc, wbf);
    // 2. mega1: stoken (staged K-loop) + q/k + v (128x128 one-shot)
    mega1_kernel<<<896, 256, 0, stream>>>(aff, xn_cn, xn_nc, wbf,
                                          qk_nc, v_cn, stoken_part, rs_part);
    // 3. stmd (64 blocks) + lepe conv (512 blocks)
    stmd_lepe_kernel<<<576, 256, 0, stream>>>(stoken_part, wbf + 3 * 65536,
                                              st_md, rs_part,
                                              v_cn, lw, lb, lepe_cn);
    // 4. stage-1 attention partials, m-split (grid 1024, 18.4KB LDS)
    mega2_kernel<<<1024, 256, 0, stream>>>(qk_nc, v_cn, st_md, opart);
    // 5. merge -> sout_bf
    merge1_kernel<<<1024, 256, 0, stream>>>(opart, sout_bf);
    // 6. stage-2 attention, n-split (grid 32x32) + lepe add -> d_out
    stage2_mfma<<<dim3(32, 32), 256, 0, stream>>>(qk_nc, st_md, sout_bf, lepe_cn, out);
}